// Round 11
// baseline (522.643 us; speedup 1.0000x reference)
//
#include <hip/hip_runtime.h>
#include <hip/hip_bf16.h>
#include <cstdint>

typedef unsigned short ushort_t;
typedef float f32x2 __attribute__((ext_vector_type(2)));

__device__ __forceinline__ float softplus2(float x){
    return fmaxf(x, 0.f) + __logf(1.f + __expf(-fabsf(x)));
}
__device__ __forceinline__ float siluf(float x){
    return x / (1.f + __expf(-x));
}
__device__ __forceinline__ float b2f(ushort_t u){
    union { uint32_t i; float f; } v; v.i = ((uint32_t)u)<<16; return v.f;
}
__device__ __forceinline__ ushort_t f2b(float f){
    uint32_t x = __float_as_uint(f);
    uint32_t r = (x + 0x7FFFu + ((x>>16)&1u)) >> 16;
    return (ushort_t)r;
}
__device__ __forceinline__ f32x2 m2(f32x2 v, float s){ f32x2 r; r.x=v.x*s; r.y=v.y*s; return r; }

struct AxialParams {
    const float* kh[3]; const float* kw[3]; const float* k3[3];
    const float* g[3];  const float* b[3];
};

// ---- K1: axial depthwise chain (kw -> kh -> 3x3) + BN + residual (f32 in, f32 out) ----
__global__ __launch_bounds__(256) void k_axial(const float* __restrict__ x,
                                               float* __restrict__ Y0, AxialParams P){
    __shared__ float s0[4096];
    __shared__ float s1[4096];
    int bid = blockIdx.x;
    int i = bid >> 8;
    int rem = bid & 255;
    int b = rem >> 5, c = rem & 31;
    int dil = i + 1;
    const float* xin = x + ((size_t)(b*128 + i*32 + c))*4096;
    float wkw[7], wkh[7], wk3[9];
    #pragma unroll
    for(int t=0;t<7;t++){ wkw[t]=P.kw[i][c*7+t]; wkh[t]=P.kh[i][c*7+t]; }
    #pragma unroll
    for(int t=0;t<9;t++) wk3[t]=P.k3[i][c*9+t];
    float gc = P.g[i][c], bc = P.b[i][c];
    int tid = threadIdx.x;
    for(int idx=tid; idx<4096; idx+=256) s0[idx]=xin[idx];
    __syncthreads();
    for(int idx=tid; idx<4096; idx+=256){
        int h=idx>>6, w=idx&63; float a=0.f;
        #pragma unroll
        for(int t=0;t<7;t++){ int ww=w+(t-3)*dil; if(ww>=0&&ww<64) a=fmaf(s0[h*64+ww],wkw[t],a); }
        s1[idx]=a;
    }
    __syncthreads();
    for(int idx=tid; idx<4096; idx+=256){
        int h=idx>>6, w=idx&63; float a=0.f;
        #pragma unroll
        for(int t=0;t<7;t++){ int hh=h+(t-3)*dil; if(hh>=0&&hh<64) a=fmaf(s1[hh*64+w],wkh[t],a); }
        s0[idx]=a;
    }
    __syncthreads();
    const float inv = rsqrtf(1.00001f);
    float* out = Y0 + ((size_t)(i*8+b)*32 + c)*4096;
    for(int idx=tid; idx<4096; idx+=256){
        int h=idx>>6, w=idx&63; float a=0.f;
        #pragma unroll
        for(int t=0;t<9;t++){
            int hh=h+((t/3)-1)*dil, ww=w+((t%3)-1)*dil;
            if(hh>=0&&hh<64&&ww>=0&&ww<64) a=fmaf(s0[hh*64+ww],wk3[t],a);
        }
        out[idx] = a*inv*gc + bc + xin[idx];
    }
}

// ---- K2: channel LayerNorm(32) + in_proj (32->128) -> XW (bf16), ZS = silu(z) (bf16) ----
__global__ __launch_bounds__(256) void k_lnproj(const float* __restrict__ Y0,
        const float* __restrict__ ln_g, const float* __restrict__ ln_b,
        const float* __restrict__ in_w, ushort_t* __restrict__ XW, ushort_t* __restrict__ ZS){
    __shared__ float W[128*32];
    int tid=threadIdx.x;
    for(int idx=tid; idx<1024; idx+=256)
        *reinterpret_cast<float4*>(&W[idx*4]) = *reinterpret_cast<const float4*>(&in_w[idx*4]);
    __syncthreads();
    int pg = blockIdx.x*256 + tid;
    int ib = pg>>12, p = pg&4095;
    const float* src = Y0 + (size_t)ib*32*4096;
    float t[32];
    float mu=0.f;
    #pragma unroll
    for(int c=0;c<32;c++){ t[c]=src[c*4096+p]; mu+=t[c]; }
    mu *= (1.f/32.f);
    float v=0.f;
    #pragma unroll
    for(int c=0;c<32;c++){ float d=t[c]-mu; v+=d*d; }
    v *= (1.f/32.f);
    float rs = rsqrtf(v+1e-5f);
    #pragma unroll
    for(int c=0;c<32;c++) t[c] = (t[c]-mu)*rs*ln_g[c] + ln_b[c];
    ushort_t* xw = XW + (size_t)ib*64*4096 + p;
    ushort_t* zs = ZS + (size_t)ib*64*4096 + p;
    for(int j=0;j<64;j++){
        float wv[32], wv2[32];
        const float4* wp  = reinterpret_cast<const float4*>(&W[j*32]);
        const float4* wp2 = reinterpret_cast<const float4*>(&W[(j+64)*32]);
        #pragma unroll
        for(int q=0;q<8;q++){
            *reinterpret_cast<float4*>(&wv[q*4])  = wp[q];
            *reinterpret_cast<float4*>(&wv2[q*4]) = wp2[q];
        }
        float a=0.f, a2=0.f;
        #pragma unroll
        for(int c=0;c<32;c++){
            a  = fmaf(t[c], wv[c],  a);
            a2 = fmaf(t[c], wv2[c], a2);
        }
        xw[(size_t)j*4096] = f2b(a);
        zs[(size_t)j*4096] = f2b(siluf(a2));
    }
}

// ---- K3: fused depthwise 3x3 + bias + silu -> XC AND XCT (transposed) ----
__global__ __launch_bounds__(256) void k_dwt(const ushort_t* __restrict__ XW,
        const float* __restrict__ cw, const float* __restrict__ cb,
        ushort_t* __restrict__ XC, ushort_t* __restrict__ XCT){
    __shared__ ushort_t sin_[4096];
    __shared__ ushort_t tr[64*66];
    int bid=blockIdx.x, tid=threadIdx.x;
    int d = bid&63;
    const ushort_t* src = XW + (size_t)bid*4096;
    for(int idx=tid; idx<1024; idx+=256)
        *reinterpret_cast<ushort4*>(&sin_[idx*4]) = *reinterpret_cast<const ushort4*>(&src[idx*4]);
    float wk[9];
    #pragma unroll
    for(int t=0;t<9;t++) wk[t]=cw[d*9+t];
    float bias=cb[d];
    __syncthreads();
    ushort_t* outp = XC + (size_t)bid*4096;
    for(int idx=tid; idx<4096; idx+=256){
        int h=idx>>6, wq=idx&63;
        float a=bias;
        #pragma unroll
        for(int t=0;t<9;t++){
            int hh=h+(t/3)-1, ww=wq+(t%3)-1;
            if(hh>=0&&hh<64&&ww>=0&&ww<64) a=fmaf(b2f(sin_[hh*64+ww]),wk[t],a);
        }
        ushort_t vb = f2b(siluf(a));
        outp[idx]=vb;
        tr[wq*66+h]=vb;
    }
    __syncthreads();
    ushort_t* outt = XCT + (size_t)bid*4096;
    for(int idx=tid; idx<4096; idx+=256){
        outt[idx]=tr[(idx>>6)*66+(idx&63)];
    }
}

// ---- helper: 64-dot with u in VGPRs and W row in LDS (b128 broadcast chunks) ----
__device__ __forceinline__ float dot64(const float* u, const float* Wrow){
    float acc=0.f;
    #pragma unroll
    for(int q=0;q<4;q++){
        float wv[16];
        const float4* wp = reinterpret_cast<const float4*>(Wrow + q*16);
        *reinterpret_cast<float4*>(&wv[0])  = wp[0];
        *reinterpret_cast<float4*>(&wv[4])  = wp[1];
        *reinterpret_cast<float4*>(&wv[8])  = wp[2];
        *reinterpret_cast<float4*>(&wv[12]) = wp[3];
        #pragma unroll
        for(int e=0;e<16;e++) acc = fmaf(u[q*16+e], wv[e], acc);
    }
    return acc;
}

// ---- K4: x_dbl. u[64] in VGPRs (loaded once, coalesced); both dir-pair W staged in LDS ----
__global__ __launch_bounds__(128,4) void k_xdbl(const ushort_t* __restrict__ XC, const ushort_t* __restrict__ XCT,
        const float* __restrict__ xproj, ushort_t* __restrict__ XBb, ushort_t* __restrict__ XCc,
        float* __restrict__ DT){
    __shared__ float W2[2][34*64];
    int bid=blockIdx.x, tid=threadIdx.x;
    int lb = bid&31, t=(bid>>5)&1, ib=bid>>6;
    int m = lb*128 + tid;
    for(int idx=tid; idx<2176; idx+=128){
        W2[0][idx]=xproj[t*2176+idx];
        W2[1][idx]=xproj[(t+2)*2176+idx];
    }
    const ushort_t* src = (t?XCT:XC) + (size_t)ib*64*4096;
    float u[64];
    #pragma unroll
    for(int dd=0; dd<64; dd++) u[dd] = b2f(src[(size_t)dd*4096 + m]);
    __syncthreads();
    #pragma unroll
    for(int pass=0; pass<2; ++pass){
        int k = t + 2*pass;
        const float* W = &W2[pass][0];
        int l = pass ? (4095-m) : m;
        float* dtp = DT + ((size_t)(ib*4+k)*2)*4096 + l;
        ushort_t* ob = XBb + ((size_t)(ib*4+k)*16)*4096 + l;
        ushort_t* oc = XCc + ((size_t)(ib*4+k)*16)*4096 + l;
        dtp[0]    = dot64(u, W);
        dtp[4096] = dot64(u, W+64);
        #pragma unroll 4
        for(int c=0;c<16;c++) ob[(size_t)c*4096]=f2b(dot64(u, W+(2+c)*64));
        #pragma unroll 4
        for(int c=0;c<16;c++) oc[(size_t)c*4096]=f2b(dot64(u, W+(18+c)*64));
    }
}

// ================= scan kernels (CLEN=32, 128 chunks, XCD-pair swizzled) =================
__device__ __forceinline__ int chunk_swz(int c0){
    int xcd = c0 & 7, grp = c0 >> 3;
    return (grp >> 1)*16 + xcd*2 + (grp & 1);
}

template<bool UNI>
__device__ __forceinline__ void scan1_body(int w,int d,float dt0,float dt1,float db,
    const float* An, f32x2* h2, float& S,
    const float (*sB)[32][16], const float (*sdt)[32][2], const ushort_t (*su)[66])
{
    for(int t=0;t<32;t++){
        const float* dp=&sdt[w][t][0];
        float delta=softplus2(fmaf(dt0,dp[0],fmaf(dt1,dp[1],db)));
        S+=delta;
        int j = w? 31-t : t;
        float du = delta*b2f(su[j][d]);
        float bb[16];
        const float4* bp=reinterpret_cast<const float4*>(&sB[w][t][0]);
        reinterpret_cast<float4*>(bb)[0]=bp[0];
        reinterpret_cast<float4*>(bb)[1]=bp[1];
        reinterpret_cast<float4*>(bb)[2]=bp[2];
        reinterpret_cast<float4*>(bb)[3]=bp[3];
        if(UNI){
            float r1=__expf(delta*An[0]);
            float r2=r1*r1, r4=r2*r2, r8=r4*r4;
            f32x2 a0={r1,r2};
            f32x2 aa1=m2(a0,r2), aa2=m2(a0,r4), aa3=m2(aa1,r4);
            f32x2 aa4=m2(a0,r8), aa5=m2(aa1,r8), aa6=m2(aa2,r8), aa7=m2(aa3,r8);
            f32x2 du2={du,du};
            const f32x2* b2p=reinterpret_cast<const f32x2*>(bb);
            h2[0]=h2[0]*a0 +du2*b2p[0];
            h2[1]=h2[1]*aa1+du2*b2p[1];
            h2[2]=h2[2]*aa2+du2*b2p[2];
            h2[3]=h2[3]*aa3+du2*b2p[3];
            h2[4]=h2[4]*aa4+du2*b2p[4];
            h2[5]=h2[5]*aa5+du2*b2p[5];
            h2[6]=h2[6]*aa6+du2*b2p[6];
            h2[7]=h2[7]*aa7+du2*b2p[7];
        } else {
            float* hf=reinterpret_cast<float*>(h2);
            #pragma unroll
            for(int n=0;n<16;n++){ float a=__expf(delta*An[n]); hf[n]=fmaf(hf[n],a,du*bb[n]); }
        }
    }
}

__global__ __launch_bounds__(128) void k_scan1(const ushort_t* __restrict__ XBb, const float* __restrict__ DT,
        const ushort_t* __restrict__ XC, const ushort_t* __restrict__ XCT,
        const float* __restrict__ dtw, const float* __restrict__ dtb,
        const float* __restrict__ A_logs,
        ushort_t* __restrict__ CHS, float* __restrict__ SD){
    __shared__ float sB[2][32][16];
    __shared__ float sdt[2][32][2];
    __shared__ ushort_t su[32][66];
    int bid=blockIdx.x, tid=threadIdx.x;
    int ib = bid>>8; int rem = bid&255; int p = rem>>7; int ch = chunk_swz(rem&127);
    int w = tid>>6, d = tid&63;
    int l0 = ch*32, r0 = 4064 - l0;
    const ushort_t* B0 = XBb + (size_t)(4*ib+p)*16*4096;
    const ushort_t* B1 = XBb + (size_t)(4*ib+p+2)*16*4096;
    for(int idx=tid; idx<256; idx+=128){
        int n=idx&15, qi=(idx>>4)&7, w2=idx>>7;
        int base=(w2? r0 : l0) + qi*4;
        ushort4 v = *reinterpret_cast<const ushort4*>(&(w2?B1:B0)[(size_t)n*4096 + base]);
        int sl=qi*4;
        sB[w2][sl+0][n]=b2f(v.x); sB[w2][sl+1][n]=b2f(v.y);
        sB[w2][sl+2][n]=b2f(v.z); sB[w2][sl+3][n]=b2f(v.w);
    }
    {
        const float* D0 = DT + (size_t)(4*ib+p)*2*4096;
        const float* D1 = DT + (size_t)(4*ib+p+2)*2*4096;
        int w2=tid>>6; int rem2=tid&63; int s=rem2>>1; int r=rem2&1;
        sdt[w2][s][r]      = (w2? D1 : D0)[(size_t)r*4096 + (w2? r0 : l0) + s];
        sdt[w2][s+16][r]   = (w2? D1 : D0)[(size_t)r*4096 + (w2? r0 : l0) + s + 16];
    }
    const ushort_t* U = (p?XCT:XC) + (size_t)ib*64*4096;
    for(int idx=tid; idx<512; idx+=128){
        int r=idx>>3, q=(idx&7)*4;
        ushort4 v = *reinterpret_cast<const ushort4*>(&U[(size_t)r*4096 + l0 + q]);
        su[q+0][r]=v.x; su[q+1][r]=v.y; su[q+2][r]=v.z; su[q+3][r]=v.w;
    }
    __syncthreads();
    int k = p + 2*w;
    float dt0=dtw[(k*64+d)*2], dt1=dtw[(k*64+d)*2+1], db=dtb[k*64+d];
    float An[16];
    #pragma unroll
    for(int n=0;n<16;n++) An[n] = -__expf(A_logs[(k*64+d)*16+n]);
    bool st = true;
    #pragma unroll
    for(int n=1;n<16;n++) st = st && (fabsf(An[n]-(n+1)*An[0]) <= 1e-4f*fabsf(An[n]) + 1e-6f);
    bool uni = (bool)__all((int)st);
    f32x2 h2[8];
    #pragma unroll
    for(int i=0;i<8;i++){ h2[i].x=0.f; h2[i].y=0.f; }
    float S=0.f;
    if(uni) scan1_body<true >(w,d,dt0,dt1,db,An,h2,S,sB,sdt,su);
    else    scan1_body<false>(w,d,dt0,dt1,db,An,h2,S,sB,sdt,su);
    int chd = w ? 127-ch : ch;
    ushort_t* o = CHS + ((size_t)(4*ib+k)*128 + chd)*1024 + d*16;
    const float* hf = reinterpret_cast<const float*>(h2);
    #pragma unroll
    for(int n=0;n<16;n++) o[n]=f2b(hf[n]);
    SD[((size_t)(4*ib+k)*128 + chd)*64 + d]=S;
}

// ---- K5b: chunk-level exclusive scan (128 chunks, scan order); 4-way d-split ----
__global__ __launch_bounds__(256) void k_scan2(const float* __restrict__ A_logs,
        const float* __restrict__ SD, ushort_t* __restrict__ CHS){
    __shared__ float sS[2048];
    int g=blockIdx.x; int ibk=g>>2; int dg=g&3; int tid=threadIdx.x;
    for(int idx=tid; idx<2048; idx+=256){
        int c=idx>>4, dl=idx&15;
        sS[idx]=SD[((size_t)ibk*128+c)*64 + dg*16 + dl];
    }
    __syncthreads();
    int dl=tid>>4, n=tid&15, k=ibk&3;
    int d=dg*16+dl;
    float An = -__expf(A_logs[(k*64+d)*16+n]);
    float H=0.f;
    for(int c=0;c<128;c++){
        float pc = __expf(An*sS[c*16+dl]);
        size_t o = ((size_t)ibk*128+c)*1024 + dg*256 + tid;
        float loc = b2f(CHS[o]);
        CHS[o]=f2b(H);
        H = fmaf(H, pc, loc);
    }
}

// ---- K6: re-run chunks from entry states; wave0 keeps y in regs, wave1 stores y to sy;
//      single barrier; wave0 merges and writes spatial global rows directly ----
template<bool UNI>
__device__ __forceinline__ void scan3_run(int w,int d,float dt0,float dt1,float db,
    const float* An, f32x2* h2, float* yreg,
    const float (*sB)[32][16], const float (*sC)[32][16],
    const float (*sdt)[32][2], const ushort_t (*su)[66], ushort_t (*sy)[66])
{
    #pragma unroll
    for(int t=0;t<32;t++){
        const float* dp=&sdt[w][t][0];
        float delta=softplus2(fmaf(dt0,dp[0],fmaf(dt1,dp[1],db)));
        int j = w? 31-t : t;
        float du = delta*b2f(su[j][d]);
        float bb[16], cc[16];
        const float4* bp=reinterpret_cast<const float4*>(&sB[w][t][0]);
        const float4* cp=reinterpret_cast<const float4*>(&sC[w][t][0]);
        reinterpret_cast<float4*>(bb)[0]=bp[0]; reinterpret_cast<float4*>(bb)[1]=bp[1];
        reinterpret_cast<float4*>(bb)[2]=bp[2]; reinterpret_cast<float4*>(bb)[3]=bp[3];
        reinterpret_cast<float4*>(cc)[0]=cp[0]; reinterpret_cast<float4*>(cc)[1]=cp[1];
        reinterpret_cast<float4*>(cc)[2]=cp[2]; reinterpret_cast<float4*>(cc)[3]=cp[3];
        float y;
        if(UNI){
            float r1=__expf(delta*An[0]);
            float r2=r1*r1, r4=r2*r2, r8=r4*r4;
            f32x2 a0={r1,r2};
            f32x2 aa1=m2(a0,r2), aa2=m2(a0,r4), aa3=m2(aa1,r4);
            f32x2 aa4=m2(a0,r8), aa5=m2(aa1,r8), aa6=m2(aa2,r8), aa7=m2(aa3,r8);
            f32x2 du2={du,du};
            f32x2 y2={0.f,0.f};
            const f32x2* b2p=reinterpret_cast<const f32x2*>(bb);
            const f32x2* c2p=reinterpret_cast<const f32x2*>(cc);
            h2[0]=h2[0]*a0 +du2*b2p[0]; y2=y2+h2[0]*c2p[0];
            h2[1]=h2[1]*aa1+du2*b2p[1]; y2=y2+h2[1]*c2p[1];
            h2[2]=h2[2]*aa2+du2*b2p[2]; y2=y2+h2[2]*c2p[2];
            h2[3]=h2[3]*aa3+du2*b2p[3]; y2=y2+h2[3]*c2p[3];
            h2[4]=h2[4]*aa4+du2*b2p[4]; y2=y2+h2[4]*c2p[4];
            h2[5]=h2[5]*aa5+du2*b2p[5]; y2=y2+h2[5]*c2p[5];
            h2[6]=h2[6]*aa6+du2*b2p[6]; y2=y2+h2[6]*c2p[6];
            h2[7]=h2[7]*aa7+du2*b2p[7]; y2=y2+h2[7]*c2p[7];
            y = y2.x + y2.y;
        } else {
            y=0.f;
            float* hf=reinterpret_cast<float*>(h2);
            #pragma unroll
            for(int n=0;n<16;n++){
                float a=__expf(delta*An[n]);
                hf[n]=fmaf(hf[n],a,du*bb[n]);
                y=fmaf(hf[n],cc[n],y);
            }
        }
        if(w==0) yreg[t]=y;
        else     sy[j][d]=f2b(y);
    }
}

__global__ __launch_bounds__(128,4) void k_scan3(const ushort_t* __restrict__ XBb, const ushort_t* __restrict__ XCc,
        const float* __restrict__ DT,
        const ushort_t* __restrict__ XC, const ushort_t* __restrict__ XCT,
        const float* __restrict__ dtw, const float* __restrict__ dtb,
        const float* __restrict__ A_logs,
        const ushort_t* __restrict__ CHS,
        ushort_t* __restrict__ YS){
    __shared__ float sB[2][32][16];
    __shared__ float sC[2][32][16];
    __shared__ float sdt[2][32][2];
    __shared__ ushort_t su[32][66];
    __shared__ ushort_t sy[32][66];
    int bid=blockIdx.x, tid=threadIdx.x;
    int ib = bid>>8; int rem = bid&255; int p = rem>>7; int ch = chunk_swz(rem&127);
    int w = tid>>6, d = tid&63;
    int l0 = ch*32, r0 = 4064 - l0;
    const ushort_t* B0 = XBb + (size_t)(4*ib+p)*16*4096;
    const ushort_t* B1 = XBb + (size_t)(4*ib+p+2)*16*4096;
    const ushort_t* C0 = XCc + (size_t)(4*ib+p)*16*4096;
    const ushort_t* C1 = XCc + (size_t)(4*ib+p+2)*16*4096;
    for(int idx=tid; idx<512; idx+=128){
        int n=idx&15, qi=(idx>>4)&7, w2=(idx>>7)&1, arr=idx>>8;
        int base=(w2? r0 : l0) + qi*4;
        const ushort_t* S = arr? (w2?C1:C0) : (w2?B1:B0);
        ushort4 v = *reinterpret_cast<const ushort4*>(&S[(size_t)n*4096 + base]);
        float (*dst)[32][16] = arr? sC : sB;
        int sl=qi*4;
        dst[w2][sl+0][n]=b2f(v.x); dst[w2][sl+1][n]=b2f(v.y);
        dst[w2][sl+2][n]=b2f(v.z); dst[w2][sl+3][n]=b2f(v.w);
    }
    {
        const float* D0 = DT + (size_t)(4*ib+p)*2*4096;
        const float* D1 = DT + (size_t)(4*ib+p+2)*2*4096;
        int w2=tid>>6; int rem2=tid&63; int s=rem2>>1; int r=rem2&1;
        sdt[w2][s][r]      = (w2? D1 : D0)[(size_t)r*4096 + (w2? r0 : l0) + s];
        sdt[w2][s+16][r]   = (w2? D1 : D0)[(size_t)r*4096 + (w2? r0 : l0) + s + 16];
    }
    const ushort_t* U = (p?XCT:XC) + (size_t)ib*64*4096;
    for(int idx=tid; idx<512; idx+=128){
        int r=idx>>3, q=(idx&7)*4;
        ushort4 v = *reinterpret_cast<const ushort4*>(&U[(size_t)r*4096 + l0 + q]);
        su[q+0][r]=v.x; su[q+1][r]=v.y; su[q+2][r]=v.z; su[q+3][r]=v.w;
    }
    __syncthreads();
    int k = p + 2*w;
    float dt0=dtw[(k*64+d)*2], dt1=dtw[(k*64+d)*2+1], db=dtb[k*64+d];
    float An[16];
    #pragma unroll
    for(int n=0;n<16;n++) An[n] = -__expf(A_logs[(k*64+d)*16+n]);
    bool st = true;
    #pragma unroll
    for(int n=1;n<16;n++) st = st && (fabsf(An[n]-(n+1)*An[0]) <= 1e-4f*fabsf(An[n]) + 1e-6f);
    bool uni = (bool)__all((int)st);
    int chd = w ? 127-ch : ch;
    const ushort_t* e = CHS + ((size_t)(4*ib+k)*128 + chd)*1024 + d*16;
    f32x2 h2[8];
    {
        float* hf = reinterpret_cast<float*>(h2);
        #pragma unroll
        for(int n=0;n<16;n++) hf[n]=b2f(e[n]);
    }
    float yreg[32];
    if(uni) scan3_run<true >(w,d,dt0,dt1,db,An,h2,yreg,sB,sC,sdt,su,sy);
    else    scan3_run<false>(w,d,dt0,dt1,db,An,h2,yreg,sB,sC,sdt,su,sy);
    __syncthreads();
    if(w==0){
        ushort_t* plane = YS + (size_t)(ib*2+p)*262144;
        if(p==0){
            #pragma unroll
            for(int j=0;j<32;j++)
                plane[(size_t)(l0+j)*64 + d] = f2b(yreg[j] + b2f(sy[j][d]));
        } else {
            int hi = l0>>6, lo0 = l0&63;
            #pragma unroll
            for(int j=0;j<32;j++)
                plane[(size_t)(lo0+j)*4096 + hi*64 + d] = f2b(yreg[j] + b2f(sy[j][d]));
        }
    }
}

// ---- K8: out-LN(64) + gate + out-proj + residual + scale + BN + ReLU (f32 out) ----
__global__ __launch_bounds__(256) void k_final2(const ushort_t* __restrict__ YS,
        const ushort_t* __restrict__ ZS, const float* __restrict__ Y0,
        const ushort_t* __restrict__ XC, const float* __restrict__ Ds,
        const float* __restrict__ on_g, const float* __restrict__ on_b,
        const float* __restrict__ out_w,
        const float* __restrict__ s1, const float* __restrict__ s2, const float* __restrict__ s3,
        const float* __restrict__ bn_g, const float* __restrict__ bn_b,
        float* __restrict__ out){
    __shared__ float W[32*64];
    __shared__ float sD[64];
    int tid=threadIdx.x;
    for(int idx=tid; idx<512; idx+=256)
        *reinterpret_cast<float4*>(&W[idx*4]) = *reinterpret_cast<const float4*>(&out_w[idx*4]);
    if(tid<64) sD[tid]=Ds[tid]+Ds[64+tid]+Ds[128+tid]+Ds[192+tid];
    __syncthreads();
    int pg=blockIdx.x*256+tid;
    int ib=pg>>12, p=pg&4095;
    int i=ib>>3, b=ib&7;
    const ushort_t* r0p = YS + (size_t)(ib*2+0)*262144 + (size_t)p*64;
    const ushort_t* r1p = YS + (size_t)(ib*2+1)*262144 + (size_t)p*64;
    const ushort_t* xc = XC + (size_t)ib*64*4096 + p;
    float y[64];
    float mu=0.f;
    #pragma unroll
    for(int qq=0; qq<8; ++qq){
        ushort4 a0 = reinterpret_cast<const ushort4*>(r0p)[qq*2];
        ushort4 b0 = reinterpret_cast<const ushort4*>(r0p)[qq*2+1];
        ushort4 a1 = reinterpret_cast<const ushort4*>(r1p)[qq*2];
        ushort4 b1 = reinterpret_cast<const ushort4*>(r1p)[qq*2+1];
        const ushort_t* u0=reinterpret_cast<const ushort_t*>(&a0);
        const ushort_t* u1=reinterpret_cast<const ushort_t*>(&b0);
        const ushort_t* v0=reinterpret_cast<const ushort_t*>(&a1);
        const ushort_t* v1=reinterpret_cast<const ushort_t*>(&b1);
        #pragma unroll
        for(int e=0;e<4;e++){
            int dd=qq*8+e;
            y[dd]   = b2f(u0[e])+b2f(v0[e]) + sD[dd]  *b2f(xc[(size_t)dd*4096]);
            y[dd+4] = b2f(u1[e])+b2f(v1[e]) + sD[dd+4]*b2f(xc[(size_t)(dd+4)*4096]);
            mu += y[dd]+y[dd+4];
        }
    }
    mu*=(1.f/64.f);
    float v=0.f;
    #pragma unroll
    for(int dd=0;dd<64;dd++){ float q=y[dd]-mu; v+=q*q; }
    v*=(1.f/64.f);
    float rs=rsqrtf(v+1e-5f);
    const ushort_t* zs = ZS + (size_t)ib*64*4096 + p;
    #pragma unroll
    for(int dd=0;dd<64;dd++){
        float yn=(y[dd]-mu)*rs*on_g[dd]+on_b[dd];
        y[dd]=yn*b2f(zs[(size_t)dd*4096]);
    }
    float sc = (i==0)?s1[0]:((i==1)?s2[0]:s3[0]);
    const float inv = rsqrtf(1.00001f);
    const float* y0 = Y0 + (size_t)ib*32*4096 + p;
    for(int c=0;c<32;c++){
        float wv[64];
        const float4* wp = reinterpret_cast<const float4*>(&W[c*64]);
        #pragma unroll
        for(int q=0;q<16;q++) *reinterpret_cast<float4*>(&wv[q*4]) = wp[q];
        float a=0.f;
        #pragma unroll
        for(int dd=0;dd<64;dd++) a=fmaf(y[dd],wv[dd],a);
        float o=(y0[(size_t)c*4096]+a)*sc;
        int chn=i*32+c;
        float vv=fmaf(o*inv, bn_g[chn], bn_b[chn]);
        out[((size_t)b*128+chn)*4096 + p]=fmaxf(vv,0.f);
    }
}

// ---- K9: branch 4 passthrough * scale4 + BN + ReLU (f32 out) ----
__global__ __launch_bounds__(256) void k_branch4(const float* __restrict__ x,
        const float* __restrict__ s4, const float* __restrict__ bn_g,
        const float* __restrict__ bn_b, float* __restrict__ out){
    int g=blockIdx.x*256+threadIdx.x;
    int b=g>>17; int rem=g&131071; int c=rem>>12; int p=rem&4095;
    int chn=96+c;
    const float inv=rsqrtf(1.00001f);
    float v=x[((size_t)b*128+chn)*4096+p]*s4[0];
    v=fmaf(v*inv, bn_g[chn], bn_b[chn]);
    out[((size_t)b*128+chn)*4096+p]=fmaxf(v,0.f);
}

extern "C" void kernel_launch(void* const* d_in, const int* in_sizes, int n_in,
                              void* d_out, int out_size, void* d_ws, size_t ws_size,
                              hipStream_t stream) {
    const float* x      = (const float*)d_in[0];
    const float* ln_g   = (const float*)d_in[16];
    const float* ln_b   = (const float*)d_in[17];
    const float* in_w   = (const float*)d_in[18];
    const float* conv_w = (const float*)d_in[19];
    const float* conv_b = (const float*)d_in[20];
    const float* xproj  = (const float*)d_in[21];
    const float* dtw    = (const float*)d_in[22];
    const float* dtb    = (const float*)d_in[23];
    const float* A_logs = (const float*)d_in[24];
    const float* Ds     = (const float*)d_in[25];
    const float* on_g   = (const float*)d_in[26];
    const float* on_b   = (const float*)d_in[27];
    const float* out_w  = (const float*)d_in[28];
    const float* sc1    = (const float*)d_in[29];
    const float* sc2    = (const float*)d_in[30];
    const float* sc3    = (const float*)d_in[31];
    const float* sc4    = (const float*)d_in[32];
    const float* bn_g   = (const float*)d_in[33];
    const float* bn_b   = (const float*)d_in[34];

    AxialParams P;
    for(int i=0;i<3;i++){
        P.kh[i]=(const float*)d_in[1+5*i];
        P.kw[i]=(const float*)d_in[2+5*i];
        P.k3[i]=(const float*)d_in[3+5*i];
        P.g[i] =(const float*)d_in[4+5*i];
        P.b[i] =(const float*)d_in[5+5*i];
    }

    // ---- workspace layout (bytes); total 132,120,576 ----
    char* base = (char*)d_ws;
    float*    Y0   = (float*)   (base + 0);            // 12,582,912 f32
    ushort_t* ZS   = (ushort_t*)(base + 12582912);
    ushort_t* XC   = (ushort_t*)(base + 25165824);
    ushort_t* XCT  = (ushort_t*)(base + 37748736);
    ushort_t* XBb  = (ushort_t*)(base + 50331648);     // early alias: XW
    ushort_t* XW   = (ushort_t*)(base + 50331648);
    ushort_t* XCc  = (ushort_t*)(base + 62914560);
    float*    DT   = (float*)   (base + 75497472);     //  3,145,728 f32
    ushort_t* CHS  = (ushort_t*)(base + 78643200);     // 25,165,824 bf16 (128 chunks)
    float*    SD   = (float*)   (base + 103809024);    //  3,145,728 f32
    ushort_t* YS   = (ushort_t*)(base + 106954752);    // 25,165,824 bf16 (2 spatial planes/ib)

    float* out = (float*)d_out;

    k_axial    <<<768,   256, 0, stream>>>(x, Y0, P);
    k_lnproj   <<<384,   256, 0, stream>>>(Y0, ln_g, ln_b, in_w, XW, ZS);
    k_dwt      <<<1536,  256, 0, stream>>>(XW, conv_w, conv_b, XC, XCT);
    k_xdbl     <<<1536,  128, 0, stream>>>(XC, XCT, xproj, XBb, XCc, DT);
    k_scan1    <<<6144,  128, 0, stream>>>(XBb, DT, XC, XCT, dtw, dtb, A_logs, CHS, SD);
    k_scan2    <<<384,   256, 0, stream>>>(A_logs, SD, CHS);
    k_scan3    <<<6144,  128, 0, stream>>>(XBb, XCc, DT, XC, XCT, dtw, dtb, A_logs, CHS, YS);
    k_final2   <<<384,   256, 0, stream>>>(YS, ZS, Y0, XC, Ds, on_g, on_b, out_w,
                                           sc1, sc2, sc3, bn_g, bn_b, out);
    k_branch4  <<<4096,  256, 0, stream>>>(x, sc4, bn_g, bn_b, out);
}

// Round 12
// 295.362 us; speedup vs baseline: 1.7695x; 1.7695x over previous
//
#include <hip/hip_runtime.h>
#include <hip/hip_bf16.h>
#include <cstdint>

typedef unsigned short ushort_t;
typedef float f32x2 __attribute__((ext_vector_type(2)));

__device__ __forceinline__ float softplus2(float x){
    return fmaxf(x, 0.f) + __logf(1.f + __expf(-fabsf(x)));
}
__device__ __forceinline__ float siluf(float x){
    return x / (1.f + __expf(-x));
}
__device__ __forceinline__ float b2f(ushort_t u){
    union { uint32_t i; float f; } v; v.i = ((uint32_t)u)<<16; return v.f;
}
__device__ __forceinline__ ushort_t f2b(float f){
    uint32_t x = __float_as_uint(f);
    uint32_t r = (x + 0x7FFFu + ((x>>16)&1u)) >> 16;
    return (ushort_t)r;
}
__device__ __forceinline__ f32x2 m2(f32x2 v, float s){ f32x2 r; r.x=v.x*s; r.y=v.y*s; return r; }

struct AxialParams {
    const float* kh[3]; const float* kw[3]; const float* k3[3];
    const float* g[3];  const float* b[3];
};

// ---- K1: axial depthwise chain (kw -> kh -> 3x3) + BN + residual (f32 in, f32 out) ----
__global__ __launch_bounds__(256) void k_axial(const float* __restrict__ x,
                                               float* __restrict__ Y0, AxialParams P){
    __shared__ float s0[4096];
    __shared__ float s1[4096];
    int bid = blockIdx.x;
    int i = bid >> 8;
    int rem = bid & 255;
    int b = rem >> 5, c = rem & 31;
    int dil = i + 1;
    const float* xin = x + ((size_t)(b*128 + i*32 + c))*4096;
    float wkw[7], wkh[7], wk3[9];
    #pragma unroll
    for(int t=0;t<7;t++){ wkw[t]=P.kw[i][c*7+t]; wkh[t]=P.kh[i][c*7+t]; }
    #pragma unroll
    for(int t=0;t<9;t++) wk3[t]=P.k3[i][c*9+t];
    float gc = P.g[i][c], bc = P.b[i][c];
    int tid = threadIdx.x;
    for(int idx=tid; idx<4096; idx+=256) s0[idx]=xin[idx];
    __syncthreads();
    for(int idx=tid; idx<4096; idx+=256){
        int h=idx>>6, w=idx&63; float a=0.f;
        #pragma unroll
        for(int t=0;t<7;t++){ int ww=w+(t-3)*dil; if(ww>=0&&ww<64) a=fmaf(s0[h*64+ww],wkw[t],a); }
        s1[idx]=a;
    }
    __syncthreads();
    for(int idx=tid; idx<4096; idx+=256){
        int h=idx>>6, w=idx&63; float a=0.f;
        #pragma unroll
        for(int t=0;t<7;t++){ int hh=h+(t-3)*dil; if(hh>=0&&hh<64) a=fmaf(s1[hh*64+w],wkh[t],a); }
        s0[idx]=a;
    }
    __syncthreads();
    const float inv = rsqrtf(1.00001f);
    float* out = Y0 + ((size_t)(i*8+b)*32 + c)*4096;
    for(int idx=tid; idx<4096; idx+=256){
        int h=idx>>6, w=idx&63; float a=0.f;
        #pragma unroll
        for(int t=0;t<9;t++){
            int hh=h+((t/3)-1)*dil, ww=w+((t%3)-1)*dil;
            if(hh>=0&&hh<64&&ww>=0&&ww<64) a=fmaf(s0[hh*64+ww],wk3[t],a);
        }
        out[idx] = a*inv*gc + bc + xin[idx];
    }
}

// ---- K2: channel LayerNorm(32) + in_proj (32->128) -> XW (bf16), ZS = silu(z) (bf16) ----
__global__ __launch_bounds__(256) void k_lnproj(const float* __restrict__ Y0,
        const float* __restrict__ ln_g, const float* __restrict__ ln_b,
        const float* __restrict__ in_w, ushort_t* __restrict__ XW, ushort_t* __restrict__ ZS){
    __shared__ float W[128*32];
    int tid=threadIdx.x;
    for(int idx=tid; idx<1024; idx+=256)
        *reinterpret_cast<float4*>(&W[idx*4]) = *reinterpret_cast<const float4*>(&in_w[idx*4]);
    __syncthreads();
    int pg = blockIdx.x*256 + tid;
    int ib = pg>>12, p = pg&4095;
    const float* src = Y0 + (size_t)ib*32*4096;
    float t[32];
    float mu=0.f;
    #pragma unroll
    for(int c=0;c<32;c++){ t[c]=src[c*4096+p]; mu+=t[c]; }
    mu *= (1.f/32.f);
    float v=0.f;
    #pragma unroll
    for(int c=0;c<32;c++){ float d=t[c]-mu; v+=d*d; }
    v *= (1.f/32.f);
    float rs = rsqrtf(v+1e-5f);
    #pragma unroll
    for(int c=0;c<32;c++) t[c] = (t[c]-mu)*rs*ln_g[c] + ln_b[c];
    ushort_t* xw = XW + (size_t)ib*64*4096 + p;
    ushort_t* zs = ZS + (size_t)ib*64*4096 + p;
    for(int j=0;j<64;j++){
        float wv[32], wv2[32];
        const float4* wp  = reinterpret_cast<const float4*>(&W[j*32]);
        const float4* wp2 = reinterpret_cast<const float4*>(&W[(j+64)*32]);
        #pragma unroll
        for(int q=0;q<8;q++){
            *reinterpret_cast<float4*>(&wv[q*4])  = wp[q];
            *reinterpret_cast<float4*>(&wv2[q*4]) = wp2[q];
        }
        float a=0.f, a2=0.f;
        #pragma unroll
        for(int c=0;c<32;c++){
            a  = fmaf(t[c], wv[c],  a);
            a2 = fmaf(t[c], wv2[c], a2);
        }
        xw[(size_t)j*4096] = f2b(a);
        zs[(size_t)j*4096] = f2b(siluf(a2));
    }
}

// ---- K3: fused depthwise 3x3 + bias + silu -> XC AND XCT (transposed) ----
__global__ __launch_bounds__(256) void k_dwt(const ushort_t* __restrict__ XW,
        const float* __restrict__ cw, const float* __restrict__ cb,
        ushort_t* __restrict__ XC, ushort_t* __restrict__ XCT){
    __shared__ ushort_t sin_[4096];
    __shared__ ushort_t tr[64*66];
    int bid=blockIdx.x, tid=threadIdx.x;
    int d = bid&63;
    const ushort_t* src = XW + (size_t)bid*4096;
    for(int idx=tid; idx<1024; idx+=256)
        *reinterpret_cast<ushort4*>(&sin_[idx*4]) = *reinterpret_cast<const ushort4*>(&src[idx*4]);
    float wk[9];
    #pragma unroll
    for(int t=0;t<9;t++) wk[t]=cw[d*9+t];
    float bias=cb[d];
    __syncthreads();
    ushort_t* outp = XC + (size_t)bid*4096;
    for(int idx=tid; idx<4096; idx+=256){
        int h=idx>>6, wq=idx&63;
        float a=bias;
        #pragma unroll
        for(int t=0;t<9;t++){
            int hh=h+(t/3)-1, ww=wq+(t%3)-1;
            if(hh>=0&&hh<64&&ww>=0&&ww<64) a=fmaf(b2f(sin_[hh*64+ww]),wk[t],a);
        }
        ushort_t vb = f2b(siluf(a));
        outp[idx]=vb;
        tr[wq*66+h]=vb;
    }
    __syncthreads();
    ushort_t* outt = XCT + (size_t)bid*4096;
    for(int idx=tid; idx<4096; idx+=256){
        outt[idx]=tr[(idx>>6)*66+(idx&63)];
    }
}

// ---- K4 (r10 proven form): x_dbl, merged direction pairs; u tile + Wt in LDS ----
__global__ __launch_bounds__(128) void k_xdbl(const ushort_t* __restrict__ XC, const ushort_t* __restrict__ XCT,
        const float* __restrict__ xproj, ushort_t* __restrict__ XBb, ushort_t* __restrict__ XCc,
        float* __restrict__ DT){
    __shared__ ushort_t tile[64][128];
    __shared__ float Wt[64][36];
    int bid=blockIdx.x, tid=threadIdx.x;
    int lb = bid&31, t=(bid>>5)&1, ib=bid>>6;
    int m0 = lb*128;
    const ushort_t* src = (t?XCT:XC) + (size_t)ib*64*4096;
    for(int idx=tid; idx<2048; idx+=128){
        int dd=idx>>5, q=(idx&31)*4;
        *reinterpret_cast<ushort4*>(&tile[dd][q]) =
            *reinterpret_cast<const ushort4*>(&src[(size_t)dd*4096 + m0 + q]);
    }
    int m = m0 + tid;
    for(int pass=0; pass<2; ++pass){
        int k = t + 2*pass;
        __syncthreads();
        for(int idx=tid; idx<2176; idx+=128){
            int c=idx>>6, dd=idx&63;
            Wt[dd][c]=xproj[k*2176+idx];
        }
        __syncthreads();
        float acc[34];
        #pragma unroll
        for(int c=0;c<34;c++) acc[c]=0.f;
        for(int dd=0;dd<64;dd++){
            float u = b2f(tile[dd][tid]);
            float wv[36];
            const float4* wp = reinterpret_cast<const float4*>(&Wt[dd][0]);
            *reinterpret_cast<float4*>(&wv[0])  = wp[0];
            *reinterpret_cast<float4*>(&wv[4])  = wp[1];
            *reinterpret_cast<float4*>(&wv[8])  = wp[2];
            *reinterpret_cast<float4*>(&wv[12]) = wp[3];
            *reinterpret_cast<float4*>(&wv[16]) = wp[4];
            *reinterpret_cast<float4*>(&wv[20]) = wp[5];
            *reinterpret_cast<float4*>(&wv[24]) = wp[6];
            *reinterpret_cast<float4*>(&wv[28]) = wp[7];
            *reinterpret_cast<float2*>(&wv[32]) = *reinterpret_cast<const float2*>(&Wt[dd][32]);
            #pragma unroll
            for(int c=0;c<34;c++) acc[c] = fmaf(u, wv[c], acc[c]);
        }
        int l = pass ? (4095-m) : m;
        DT[((size_t)(ib*4+k)*2)*4096 + l]   = acc[0];
        DT[((size_t)(ib*4+k)*2+1)*4096 + l] = acc[1];
        ushort_t* ob = XBb + ((size_t)(ib*4+k)*16)*4096 + l;
        ushort_t* oc = XCc + ((size_t)(ib*4+k)*16)*4096 + l;
        #pragma unroll
        for(int c=0;c<16;c++){
            ob[(size_t)c*4096]=f2b(acc[2+c]);
            oc[(size_t)c*4096]=f2b(acc[18+c]);
        }
    }
}

// ================= scan kernels (CLEN=32, 128 chunks, XCD-pair swizzled) =================
__device__ __forceinline__ int chunk_swz(int c0){
    int xcd = c0 & 7, grp = c0 >> 3;
    return (grp >> 1)*16 + xcd*2 + (grp & 1);
}

template<bool UNI>
__device__ __forceinline__ void scan1_body(int w,int d,float dt0,float dt1,float db,
    const float* An, f32x2* h2, float& S,
    const float (*sB)[32][16], const float (*sdt)[32][2], const ushort_t (*su)[66])
{
    for(int t=0;t<32;t++){
        const float* dp=&sdt[w][t][0];
        float delta=softplus2(fmaf(dt0,dp[0],fmaf(dt1,dp[1],db)));
        S+=delta;
        int j = w? 31-t : t;
        float du = delta*b2f(su[j][d]);
        float bb[16];
        const float4* bp=reinterpret_cast<const float4*>(&sB[w][t][0]);
        reinterpret_cast<float4*>(bb)[0]=bp[0];
        reinterpret_cast<float4*>(bb)[1]=bp[1];
        reinterpret_cast<float4*>(bb)[2]=bp[2];
        reinterpret_cast<float4*>(bb)[3]=bp[3];
        if(UNI){
            float r1=__expf(delta*An[0]);
            float r2=r1*r1, r4=r2*r2, r8=r4*r4;
            f32x2 a0={r1,r2};
            f32x2 aa1=m2(a0,r2), aa2=m2(a0,r4), aa3=m2(aa1,r4);
            f32x2 aa4=m2(a0,r8), aa5=m2(aa1,r8), aa6=m2(aa2,r8), aa7=m2(aa3,r8);
            f32x2 du2={du,du};
            const f32x2* b2p=reinterpret_cast<const f32x2*>(bb);
            h2[0]=h2[0]*a0 +du2*b2p[0];
            h2[1]=h2[1]*aa1+du2*b2p[1];
            h2[2]=h2[2]*aa2+du2*b2p[2];
            h2[3]=h2[3]*aa3+du2*b2p[3];
            h2[4]=h2[4]*aa4+du2*b2p[4];
            h2[5]=h2[5]*aa5+du2*b2p[5];
            h2[6]=h2[6]*aa6+du2*b2p[6];
            h2[7]=h2[7]*aa7+du2*b2p[7];
        } else {
            float* hf=reinterpret_cast<float*>(h2);
            #pragma unroll
            for(int n=0;n<16;n++){ float a=__expf(delta*An[n]); hf[n]=fmaf(hf[n],a,du*bb[n]); }
        }
    }
}

__global__ __launch_bounds__(128) void k_scan1(const ushort_t* __restrict__ XBb, const float* __restrict__ DT,
        const ushort_t* __restrict__ XC, const ushort_t* __restrict__ XCT,
        const float* __restrict__ dtw, const float* __restrict__ dtb,
        const float* __restrict__ A_logs,
        ushort_t* __restrict__ CHS, float* __restrict__ SD){
    __shared__ float sB[2][32][16];
    __shared__ float sdt[2][32][2];
    __shared__ ushort_t su[32][66];
    int bid=blockIdx.x, tid=threadIdx.x;
    int ib = bid>>8; int rem = bid&255; int p = rem>>7; int ch = chunk_swz(rem&127);
    int w = tid>>6, d = tid&63;
    int l0 = ch*32, r0 = 4064 - l0;
    const ushort_t* B0 = XBb + (size_t)(4*ib+p)*16*4096;
    const ushort_t* B1 = XBb + (size_t)(4*ib+p+2)*16*4096;
    for(int idx=tid; idx<256; idx+=128){
        int n=idx&15, qi=(idx>>4)&7, w2=idx>>7;
        int base=(w2? r0 : l0) + qi*4;
        ushort4 v = *reinterpret_cast<const ushort4*>(&(w2?B1:B0)[(size_t)n*4096 + base]);
        int sl=qi*4;
        sB[w2][sl+0][n]=b2f(v.x); sB[w2][sl+1][n]=b2f(v.y);
        sB[w2][sl+2][n]=b2f(v.z); sB[w2][sl+3][n]=b2f(v.w);
    }
    {
        const float* D0 = DT + (size_t)(4*ib+p)*2*4096;
        const float* D1 = DT + (size_t)(4*ib+p+2)*2*4096;
        int w2=tid>>6; int rem2=tid&63; int s=rem2>>1; int r=rem2&1;
        sdt[w2][s][r]      = (w2? D1 : D0)[(size_t)r*4096 + (w2? r0 : l0) + s];
        sdt[w2][s+16][r]   = (w2? D1 : D0)[(size_t)r*4096 + (w2? r0 : l0) + s + 16];
    }
    const ushort_t* U = (p?XCT:XC) + (size_t)ib*64*4096;
    for(int idx=tid; idx<512; idx+=128){
        int r=idx>>3, q=(idx&7)*4;
        ushort4 v = *reinterpret_cast<const ushort4*>(&U[(size_t)r*4096 + l0 + q]);
        su[q+0][r]=v.x; su[q+1][r]=v.y; su[q+2][r]=v.z; su[q+3][r]=v.w;
    }
    __syncthreads();
    int k = p + 2*w;
    float dt0=dtw[(k*64+d)*2], dt1=dtw[(k*64+d)*2+1], db=dtb[k*64+d];
    float An[16];
    #pragma unroll
    for(int n=0;n<16;n++) An[n] = -__expf(A_logs[(k*64+d)*16+n]);
    bool st = true;
    #pragma unroll
    for(int n=1;n<16;n++) st = st && (fabsf(An[n]-(n+1)*An[0]) <= 1e-4f*fabsf(An[n]) + 1e-6f);
    bool uni = (bool)__all((int)st);
    f32x2 h2[8];
    #pragma unroll
    for(int i=0;i<8;i++){ h2[i].x=0.f; h2[i].y=0.f; }
    float S=0.f;
    if(uni) scan1_body<true >(w,d,dt0,dt1,db,An,h2,S,sB,sdt,su);
    else    scan1_body<false>(w,d,dt0,dt1,db,An,h2,S,sB,sdt,su);
    int chd = w ? 127-ch : ch;
    ushort_t* o = CHS + ((size_t)(4*ib+k)*128 + chd)*1024 + d*16;
    const float* hf = reinterpret_cast<const float*>(h2);
    #pragma unroll
    for(int n=0;n<16;n++) o[n]=f2b(hf[n]);
    SD[((size_t)(4*ib+k)*128 + chd)*64 + d]=S;
}

// ---- K5b: chunk-level exclusive scan (128 chunks, scan order); 4-way d-split ----
__global__ __launch_bounds__(256) void k_scan2(const float* __restrict__ A_logs,
        const float* __restrict__ SD, ushort_t* __restrict__ CHS){
    __shared__ float sS[2048];
    int g=blockIdx.x; int ibk=g>>2; int dg=g&3; int tid=threadIdx.x;
    for(int idx=tid; idx<2048; idx+=256){
        int c=idx>>4, dl=idx&15;
        sS[idx]=SD[((size_t)ibk*128+c)*64 + dg*16 + dl];
    }
    __syncthreads();
    int dl=tid>>4, n=tid&15, k=ibk&3;
    int d=dg*16+dl;
    float An = -__expf(A_logs[(k*64+d)*16+n]);
    float H=0.f;
    for(int c=0;c<128;c++){
        float pc = __expf(An*sS[c*16+dl]);
        size_t o = ((size_t)ibk*128+c)*1024 + dg*256 + tid;
        float loc = b2f(CHS[o]);
        CHS[o]=f2b(H);
        H = fmaf(H, pc, loc);
    }
}

// ---- K6: re-run chunks from entry states; wave0 keeps y in regs, wave1 stores y to sy;
//      single barrier; wave0 merges and writes spatial global rows directly ----
template<bool UNI>
__device__ __forceinline__ void scan3_run(int w,int d,float dt0,float dt1,float db,
    const float* An, f32x2* h2, float* yreg,
    const float (*sB)[32][16], const float (*sC)[32][16],
    const float (*sdt)[32][2], const ushort_t (*su)[66], ushort_t (*sy)[66])
{
    #pragma unroll
    for(int t=0;t<32;t++){
        const float* dp=&sdt[w][t][0];
        float delta=softplus2(fmaf(dt0,dp[0],fmaf(dt1,dp[1],db)));
        int j = w? 31-t : t;
        float du = delta*b2f(su[j][d]);
        float bb[16], cc[16];
        const float4* bp=reinterpret_cast<const float4*>(&sB[w][t][0]);
        const float4* cp=reinterpret_cast<const float4*>(&sC[w][t][0]);
        reinterpret_cast<float4*>(bb)[0]=bp[0]; reinterpret_cast<float4*>(bb)[1]=bp[1];
        reinterpret_cast<float4*>(bb)[2]=bp[2]; reinterpret_cast<float4*>(bb)[3]=bp[3];
        reinterpret_cast<float4*>(cc)[0]=cp[0]; reinterpret_cast<float4*>(cc)[1]=cp[1];
        reinterpret_cast<float4*>(cc)[2]=cp[2]; reinterpret_cast<float4*>(cc)[3]=cp[3];
        float y;
        if(UNI){
            float r1=__expf(delta*An[0]);
            float r2=r1*r1, r4=r2*r2, r8=r4*r4;
            f32x2 a0={r1,r2};
            f32x2 aa1=m2(a0,r2), aa2=m2(a0,r4), aa3=m2(aa1,r4);
            f32x2 aa4=m2(a0,r8), aa5=m2(aa1,r8), aa6=m2(aa2,r8), aa7=m2(aa3,r8);
            f32x2 du2={du,du};
            f32x2 y2={0.f,0.f};
            const f32x2* b2p=reinterpret_cast<const f32x2*>(bb);
            const f32x2* c2p=reinterpret_cast<const f32x2*>(cc);
            h2[0]=h2[0]*a0 +du2*b2p[0]; y2=y2+h2[0]*c2p[0];
            h2[1]=h2[1]*aa1+du2*b2p[1]; y2=y2+h2[1]*c2p[1];
            h2[2]=h2[2]*aa2+du2*b2p[2]; y2=y2+h2[2]*c2p[2];
            h2[3]=h2[3]*aa3+du2*b2p[3]; y2=y2+h2[3]*c2p[3];
            h2[4]=h2[4]*aa4+du2*b2p[4]; y2=y2+h2[4]*c2p[4];
            h2[5]=h2[5]*aa5+du2*b2p[5]; y2=y2+h2[5]*c2p[5];
            h2[6]=h2[6]*aa6+du2*b2p[6]; y2=y2+h2[6]*c2p[6];
            h2[7]=h2[7]*aa7+du2*b2p[7]; y2=y2+h2[7]*c2p[7];
            y = y2.x + y2.y;
        } else {
            y=0.f;
            float* hf=reinterpret_cast<float*>(h2);
            #pragma unroll
            for(int n=0;n<16;n++){
                float a=__expf(delta*An[n]);
                hf[n]=fmaf(hf[n],a,du*bb[n]);
                y=fmaf(hf[n],cc[n],y);
            }
        }
        if(w==0) yreg[t]=y;
        else     sy[j][d]=f2b(y);
    }
}

__global__ __launch_bounds__(128,4) void k_scan3(const ushort_t* __restrict__ XBb, const ushort_t* __restrict__ XCc,
        const float* __restrict__ DT,
        const ushort_t* __restrict__ XC, const ushort_t* __restrict__ XCT,
        const float* __restrict__ dtw, const float* __restrict__ dtb,
        const float* __restrict__ A_logs,
        const ushort_t* __restrict__ CHS,
        ushort_t* __restrict__ YS){
    __shared__ float sB[2][32][16];
    __shared__ float sC[2][32][16];
    __shared__ float sdt[2][32][2];
    __shared__ ushort_t su[32][66];
    __shared__ ushort_t sy[32][66];
    int bid=blockIdx.x, tid=threadIdx.x;
    int ib = bid>>8; int rem = bid&255; int p = rem>>7; int ch = chunk_swz(rem&127);
    int w = tid>>6, d = tid&63;
    int l0 = ch*32, r0 = 4064 - l0;
    const ushort_t* B0 = XBb + (size_t)(4*ib+p)*16*4096;
    const ushort_t* B1 = XBb + (size_t)(4*ib+p+2)*16*4096;
    const ushort_t* C0 = XCc + (size_t)(4*ib+p)*16*4096;
    const ushort_t* C1 = XCc + (size_t)(4*ib+p+2)*16*4096;
    for(int idx=tid; idx<512; idx+=128){
        int n=idx&15, qi=(idx>>4)&7, w2=(idx>>7)&1, arr=idx>>8;
        int base=(w2? r0 : l0) + qi*4;
        const ushort_t* S = arr? (w2?C1:C0) : (w2?B1:B0);
        ushort4 v = *reinterpret_cast<const ushort4*>(&S[(size_t)n*4096 + base]);
        float (*dst)[32][16] = arr? sC : sB;
        int sl=qi*4;
        dst[w2][sl+0][n]=b2f(v.x); dst[w2][sl+1][n]=b2f(v.y);
        dst[w2][sl+2][n]=b2f(v.z); dst[w2][sl+3][n]=b2f(v.w);
    }
    {
        const float* D0 = DT + (size_t)(4*ib+p)*2*4096;
        const float* D1 = DT + (size_t)(4*ib+p+2)*2*4096;
        int w2=tid>>6; int rem2=tid&63; int s=rem2>>1; int r=rem2&1;
        sdt[w2][s][r]      = (w2? D1 : D0)[(size_t)r*4096 + (w2? r0 : l0) + s];
        sdt[w2][s+16][r]   = (w2? D1 : D0)[(size_t)r*4096 + (w2? r0 : l0) + s + 16];
    }
    const ushort_t* U = (p?XCT:XC) + (size_t)ib*64*4096;
    for(int idx=tid; idx<512; idx+=128){
        int r=idx>>3, q=(idx&7)*4;
        ushort4 v = *reinterpret_cast<const ushort4*>(&U[(size_t)r*4096 + l0 + q]);
        su[q+0][r]=v.x; su[q+1][r]=v.y; su[q+2][r]=v.z; su[q+3][r]=v.w;
    }
    __syncthreads();
    int k = p + 2*w;
    float dt0=dtw[(k*64+d)*2], dt1=dtw[(k*64+d)*2+1], db=dtb[k*64+d];
    float An[16];
    #pragma unroll
    for(int n=0;n<16;n++) An[n] = -__expf(A_logs[(k*64+d)*16+n]);
    bool st = true;
    #pragma unroll
    for(int n=1;n<16;n++) st = st && (fabsf(An[n]-(n+1)*An[0]) <= 1e-4f*fabsf(An[n]) + 1e-6f);
    bool uni = (bool)__all((int)st);
    int chd = w ? 127-ch : ch;
    const ushort_t* e = CHS + ((size_t)(4*ib+k)*128 + chd)*1024 + d*16;
    f32x2 h2[8];
    {
        float* hf = reinterpret_cast<float*>(h2);
        #pragma unroll
        for(int n=0;n<16;n++) hf[n]=b2f(e[n]);
    }
    float yreg[32];
    if(uni) scan3_run<true >(w,d,dt0,dt1,db,An,h2,yreg,sB,sC,sdt,su,sy);
    else    scan3_run<false>(w,d,dt0,dt1,db,An,h2,yreg,sB,sC,sdt,su,sy);
    __syncthreads();
    if(w==0){
        ushort_t* plane = YS + (size_t)(ib*2+p)*262144;
        if(p==0){
            #pragma unroll
            for(int j=0;j<32;j++)
                plane[(size_t)(l0+j)*64 + d] = f2b(yreg[j] + b2f(sy[j][d]));
        } else {
            int hi = l0>>6, lo0 = l0&63;
            #pragma unroll
            for(int j=0;j<32;j++)
                plane[(size_t)(lo0+j)*4096 + hi*64 + d] = f2b(yreg[j] + b2f(sy[j][d]));
        }
    }
}

// ---- K8: out-LN(64) + gate + out-proj + residual + scale + BN + ReLU (f32 out) ----
__global__ __launch_bounds__(256) void k_final2(const ushort_t* __restrict__ YS,
        const ushort_t* __restrict__ ZS, const float* __restrict__ Y0,
        const ushort_t* __restrict__ XC, const float* __restrict__ Ds,
        const float* __restrict__ on_g, const float* __restrict__ on_b,
        const float* __restrict__ out_w,
        const float* __restrict__ s1, const float* __restrict__ s2, const float* __restrict__ s3,
        const float* __restrict__ bn_g, const float* __restrict__ bn_b,
        float* __restrict__ out){
    __shared__ float W[32*64];
    __shared__ float sD[64];
    int tid=threadIdx.x;
    for(int idx=tid; idx<512; idx+=256)
        *reinterpret_cast<float4*>(&W[idx*4]) = *reinterpret_cast<const float4*>(&out_w[idx*4]);
    if(tid<64) sD[tid]=Ds[tid]+Ds[64+tid]+Ds[128+tid]+Ds[192+tid];
    __syncthreads();
    int pg=blockIdx.x*256+tid;
    int ib=pg>>12, p=pg&4095;
    int i=ib>>3, b=ib&7;
    const ushort_t* r0p = YS + (size_t)(ib*2+0)*262144 + (size_t)p*64;
    const ushort_t* r1p = YS + (size_t)(ib*2+1)*262144 + (size_t)p*64;
    const ushort_t* xc = XC + (size_t)ib*64*4096 + p;
    float y[64];
    float mu=0.f;
    #pragma unroll
    for(int qq=0; qq<8; ++qq){
        ushort4 a0 = reinterpret_cast<const ushort4*>(r0p)[qq*2];
        ushort4 b0 = reinterpret_cast<const ushort4*>(r0p)[qq*2+1];
        ushort4 a1 = reinterpret_cast<const ushort4*>(r1p)[qq*2];
        ushort4 b1 = reinterpret_cast<const ushort4*>(r1p)[qq*2+1];
        const ushort_t* u0=reinterpret_cast<const ushort_t*>(&a0);
        const ushort_t* u1=reinterpret_cast<const ushort_t*>(&b0);
        const ushort_t* v0=reinterpret_cast<const ushort_t*>(&a1);
        const ushort_t* v1=reinterpret_cast<const ushort_t*>(&b1);
        #pragma unroll
        for(int e=0;e<4;e++){
            int dd=qq*8+e;
            y[dd]   = b2f(u0[e])+b2f(v0[e]) + sD[dd]  *b2f(xc[(size_t)dd*4096]);
            y[dd+4] = b2f(u1[e])+b2f(v1[e]) + sD[dd+4]*b2f(xc[(size_t)(dd+4)*4096]);
            mu += y[dd]+y[dd+4];
        }
    }
    mu*=(1.f/64.f);
    float v=0.f;
    #pragma unroll
    for(int dd=0;dd<64;dd++){ float q=y[dd]-mu; v+=q*q; }
    v*=(1.f/64.f);
    float rs=rsqrtf(v+1e-5f);
    const ushort_t* zs = ZS + (size_t)ib*64*4096 + p;
    #pragma unroll
    for(int dd=0;dd<64;dd++){
        float yn=(y[dd]-mu)*rs*on_g[dd]+on_b[dd];
        y[dd]=yn*b2f(zs[(size_t)dd*4096]);
    }
    float sc = (i==0)?s1[0]:((i==1)?s2[0]:s3[0]);
    const float inv = rsqrtf(1.00001f);
    const float* y0 = Y0 + (size_t)ib*32*4096 + p;
    for(int c=0;c<32;c++){
        float wv[64];
        const float4* wp = reinterpret_cast<const float4*>(&W[c*64]);
        #pragma unroll
        for(int q=0;q<16;q++) *reinterpret_cast<float4*>(&wv[q*4]) = wp[q];
        float a=0.f;
        #pragma unroll
        for(int dd=0;dd<64;dd++) a=fmaf(y[dd],wv[dd],a);
        float o=(y0[(size_t)c*4096]+a)*sc;
        int chn=i*32+c;
        float vv=fmaf(o*inv, bn_g[chn], bn_b[chn]);
        out[((size_t)b*128+chn)*4096 + p]=fmaxf(vv,0.f);
    }
}

// ---- K9: branch 4 passthrough * scale4 + BN + ReLU (f32 out) ----
__global__ __launch_bounds__(256) void k_branch4(const float* __restrict__ x,
        const float* __restrict__ s4, const float* __restrict__ bn_g,
        const float* __restrict__ bn_b, float* __restrict__ out){
    int g=blockIdx.x*256+threadIdx.x;
    int b=g>>17; int rem=g&131071; int c=rem>>12; int p=rem&4095;
    int chn=96+c;
    const float inv=rsqrtf(1.00001f);
    float v=x[((size_t)b*128+chn)*4096+p]*s4[0];
    v=fmaf(v*inv, bn_g[chn], bn_b[chn]);
    out[((size_t)b*128+chn)*4096+p]=fmaxf(v,0.f);
}

extern "C" void kernel_launch(void* const* d_in, const int* in_sizes, int n_in,
                              void* d_out, int out_size, void* d_ws, size_t ws_size,
                              hipStream_t stream) {
    const float* x      = (const float*)d_in[0];
    const float* ln_g   = (const float*)d_in[16];
    const float* ln_b   = (const float*)d_in[17];
    const float* in_w   = (const float*)d_in[18];
    const float* conv_w = (const float*)d_in[19];
    const float* conv_b = (const float*)d_in[20];
    const float* xproj  = (const float*)d_in[21];
    const float* dtw    = (const float*)d_in[22];
    const float* dtb    = (const float*)d_in[23];
    const float* A_logs = (const float*)d_in[24];
    const float* Ds     = (const float*)d_in[25];
    const float* on_g   = (const float*)d_in[26];
    const float* on_b   = (const float*)d_in[27];
    const float* out_w  = (const float*)d_in[28];
    const float* sc1    = (const float*)d_in[29];
    const float* sc2    = (const float*)d_in[30];
    const float* sc3    = (const float*)d_in[31];
    const float* sc4    = (const float*)d_in[32];
    const float* bn_g   = (const float*)d_in[33];
    const float* bn_b   = (const float*)d_in[34];

    AxialParams P;
    for(int i=0;i<3;i++){
        P.kh[i]=(const float*)d_in[1+5*i];
        P.kw[i]=(const float*)d_in[2+5*i];
        P.k3[i]=(const float*)d_in[3+5*i];
        P.g[i] =(const float*)d_in[4+5*i];
        P.b[i] =(const float*)d_in[5+5*i];
    }

    // ---- workspace layout (bytes); total 132,120,576 ----
    char* base = (char*)d_ws;
    float*    Y0   = (float*)   (base + 0);            // 12,582,912 f32
    ushort_t* ZS   = (ushort_t*)(base + 12582912);
    ushort_t* XC   = (ushort_t*)(base + 25165824);
    ushort_t* XCT  = (ushort_t*)(base + 37748736);
    ushort_t* XBb  = (ushort_t*)(base + 50331648);     // early alias: XW
    ushort_t* XW   = (ushort_t*)(base + 50331648);
    ushort_t* XCc  = (ushort_t*)(base + 62914560);
    float*    DT   = (float*)   (base + 75497472);     //  3,145,728 f32
    ushort_t* CHS  = (ushort_t*)(base + 78643200);     // 25,165,824 bf16 (128 chunks)
    float*    SD   = (float*)   (base + 103809024);    //  3,145,728 f32
    ushort_t* YS   = (ushort_t*)(base + 106954752);    // 25,165,824 bf16 (2 spatial planes/ib)

    float* out = (float*)d_out;

    k_axial    <<<768,   256, 0, stream>>>(x, Y0, P);
    k_lnproj   <<<384,   256, 0, stream>>>(Y0, ln_g, ln_b, in_w, XW, ZS);
    k_dwt      <<<1536,  256, 0, stream>>>(XW, conv_w, conv_b, XC, XCT);
    k_xdbl     <<<1536,  128, 0, stream>>>(XC, XCT, xproj, XBb, XCc, DT);
    k_scan1    <<<6144,  128, 0, stream>>>(XBb, DT, XC, XCT, dtw, dtb, A_logs, CHS, SD);
    k_scan2    <<<384,   256, 0, stream>>>(A_logs, SD, CHS);
    k_scan3    <<<6144,  128, 0, stream>>>(XBb, XCc, DT, XC, XCT, dtw, dtb, A_logs, CHS, YS);
    k_final2   <<<384,   256, 0, stream>>>(YS, ZS, Y0, XC, Ds, on_g, on_b, out_w,
                                           sc1, sc2, sc3, bn_g, bn_b, out);
    k_branch4  <<<4096,  256, 0, stream>>>(x, sc4, bn_g, bn_b, out);
}

// Round 13
// 290.444 us; speedup vs baseline: 1.7995x; 1.0169x over previous
//
#include <hip/hip_runtime.h>
#include <hip/hip_bf16.h>
#include <cstdint>

typedef unsigned short ushort_t;
typedef float f32x2 __attribute__((ext_vector_type(2)));

__device__ __forceinline__ float softplus2(float x){
    return fmaxf(x, 0.f) + __logf(1.f + __expf(-fabsf(x)));
}
__device__ __forceinline__ float siluf(float x){
    return x / (1.f + __expf(-x));
}
__device__ __forceinline__ float b2f(ushort_t u){
    union { uint32_t i; float f; } v; v.i = ((uint32_t)u)<<16; return v.f;
}
__device__ __forceinline__ ushort_t f2b(float f){
    uint32_t x = __float_as_uint(f);
    uint32_t r = (x + 0x7FFFu + ((x>>16)&1u)) >> 16;
    return (ushort_t)r;
}
__device__ __forceinline__ f32x2 m2(f32x2 v, float s){ f32x2 r; r.x=v.x*s; r.y=v.y*s; return r; }

struct AxialParams {
    const float* kh[3]; const float* kw[3]; const float* k3[3];
    const float* g[3];  const float* b[3];
};

// ---- K1: axial depthwise chain (kw -> kh -> 3x3) + BN + residual (f32 in, f32 out) ----
__global__ __launch_bounds__(256) void k_axial(const float* __restrict__ x,
                                               float* __restrict__ Y0, AxialParams P){
    __shared__ float s0[4096];
    __shared__ float s1[4096];
    int bid = blockIdx.x;
    int i = bid >> 8;
    int rem = bid & 255;
    int b = rem >> 5, c = rem & 31;
    int dil = i + 1;
    const float* xin = x + ((size_t)(b*128 + i*32 + c))*4096;
    float wkw[7], wkh[7], wk3[9];
    #pragma unroll
    for(int t=0;t<7;t++){ wkw[t]=P.kw[i][c*7+t]; wkh[t]=P.kh[i][c*7+t]; }
    #pragma unroll
    for(int t=0;t<9;t++) wk3[t]=P.k3[i][c*9+t];
    float gc = P.g[i][c], bc = P.b[i][c];
    int tid = threadIdx.x;
    for(int idx=tid; idx<4096; idx+=256) s0[idx]=xin[idx];
    __syncthreads();
    for(int idx=tid; idx<4096; idx+=256){
        int h=idx>>6, w=idx&63; float a=0.f;
        #pragma unroll
        for(int t=0;t<7;t++){ int ww=w+(t-3)*dil; if(ww>=0&&ww<64) a=fmaf(s0[h*64+ww],wkw[t],a); }
        s1[idx]=a;
    }
    __syncthreads();
    for(int idx=tid; idx<4096; idx+=256){
        int h=idx>>6, w=idx&63; float a=0.f;
        #pragma unroll
        for(int t=0;t<7;t++){ int hh=h+(t-3)*dil; if(hh>=0&&hh<64) a=fmaf(s1[hh*64+w],wkh[t],a); }
        s0[idx]=a;
    }
    __syncthreads();
    const float inv = rsqrtf(1.00001f);
    float* out = Y0 + ((size_t)(i*8+b)*32 + c)*4096;
    for(int idx=tid; idx<4096; idx+=256){
        int h=idx>>6, w=idx&63; float a=0.f;
        #pragma unroll
        for(int t=0;t<9;t++){
            int hh=h+((t/3)-1)*dil, ww=w+((t%3)-1)*dil;
            if(hh>=0&&hh<64&&ww>=0&&ww<64) a=fmaf(s0[hh*64+ww],wk3[t],a);
        }
        out[idx] = a*inv*gc + bc + xin[idx];
    }
}

// ---- K2: channel LayerNorm(32) + in_proj (32->128) -> XW (bf16), ZS = silu(z) (bf16) ----
__global__ __launch_bounds__(256) void k_lnproj(const float* __restrict__ Y0,
        const float* __restrict__ ln_g, const float* __restrict__ ln_b,
        const float* __restrict__ in_w, ushort_t* __restrict__ XW, ushort_t* __restrict__ ZS){
    __shared__ float W[128*32];
    int tid=threadIdx.x;
    for(int idx=tid; idx<1024; idx+=256)
        *reinterpret_cast<float4*>(&W[idx*4]) = *reinterpret_cast<const float4*>(&in_w[idx*4]);
    __syncthreads();
    int pg = blockIdx.x*256 + tid;
    int ib = pg>>12, p = pg&4095;
    const float* src = Y0 + (size_t)ib*32*4096;
    float t[32];
    float mu=0.f;
    #pragma unroll
    for(int c=0;c<32;c++){ t[c]=src[c*4096+p]; mu+=t[c]; }
    mu *= (1.f/32.f);
    float v=0.f;
    #pragma unroll
    for(int c=0;c<32;c++){ float d=t[c]-mu; v+=d*d; }
    v *= (1.f/32.f);
    float rs = rsqrtf(v+1e-5f);
    #pragma unroll
    for(int c=0;c<32;c++) t[c] = (t[c]-mu)*rs*ln_g[c] + ln_b[c];
    ushort_t* xw = XW + (size_t)ib*64*4096 + p;
    ushort_t* zs = ZS + (size_t)ib*64*4096 + p;
    for(int j=0;j<64;j++){
        float wv[32], wv2[32];
        const float4* wp  = reinterpret_cast<const float4*>(&W[j*32]);
        const float4* wp2 = reinterpret_cast<const float4*>(&W[(j+64)*32]);
        #pragma unroll
        for(int q=0;q<8;q++){
            *reinterpret_cast<float4*>(&wv[q*4])  = wp[q];
            *reinterpret_cast<float4*>(&wv2[q*4]) = wp2[q];
        }
        float a=0.f, a2=0.f;
        #pragma unroll
        for(int c=0;c<32;c++){
            a  = fmaf(t[c], wv[c],  a);
            a2 = fmaf(t[c], wv2[c], a2);
        }
        xw[(size_t)j*4096] = f2b(a);
        zs[(size_t)j*4096] = f2b(siluf(a2));
    }
}

// ---- K3: fused depthwise 3x3 + bias + silu -> XC AND XCT (transposed) ----
__global__ __launch_bounds__(256) void k_dwt(const ushort_t* __restrict__ XW,
        const float* __restrict__ cw, const float* __restrict__ cb,
        ushort_t* __restrict__ XC, ushort_t* __restrict__ XCT){
    __shared__ ushort_t sin_[4096];
    __shared__ ushort_t tr[64*66];
    int bid=blockIdx.x, tid=threadIdx.x;
    int d = bid&63;
    const ushort_t* src = XW + (size_t)bid*4096;
    for(int idx=tid; idx<1024; idx+=256)
        *reinterpret_cast<ushort4*>(&sin_[idx*4]) = *reinterpret_cast<const ushort4*>(&src[idx*4]);
    float wk[9];
    #pragma unroll
    for(int t=0;t<9;t++) wk[t]=cw[d*9+t];
    float bias=cb[d];
    __syncthreads();
    ushort_t* outp = XC + (size_t)bid*4096;
    for(int idx=tid; idx<4096; idx+=256){
        int h=idx>>6, wq=idx&63;
        float a=bias;
        #pragma unroll
        for(int t=0;t<9;t++){
            int hh=h+(t/3)-1, ww=wq+(t%3)-1;
            if(hh>=0&&hh<64&&ww>=0&&ww<64) a=fmaf(b2f(sin_[hh*64+ww]),wk[t],a);
        }
        ushort_t vb = f2b(siluf(a));
        outp[idx]=vb;
        tr[wq*66+h]=vb;
    }
    __syncthreads();
    ushort_t* outt = XCT + (size_t)bid*4096;
    for(int idx=tid; idx<4096; idx+=256){
        outt[idx]=tr[(idx>>6)*66+(idx&63)];
    }
}

// ---- K4: x_dbl, 2 pixels/thread (W-row LDS reads amortized over both) ----
__global__ __launch_bounds__(128,1) void k_xdbl(const ushort_t* __restrict__ XC, const ushort_t* __restrict__ XCT,
        const float* __restrict__ xproj, ushort_t* __restrict__ XBb, ushort_t* __restrict__ XCc,
        float* __restrict__ DT){
    __shared__ ushort_t tile[64][256];
    __shared__ float Wt[64][36];
    int bid=blockIdx.x, tid=threadIdx.x;
    int lb = bid&15, t=(bid>>4)&1, ib=bid>>5;
    int m0 = lb*256;
    const ushort_t* src = (t?XCT:XC) + (size_t)ib*64*4096;
    for(int idx=tid; idx<4096; idx+=128){
        int dd=idx>>6, q=(idx&63)*4;
        *reinterpret_cast<ushort4*>(&tile[dd][q]) =
            *reinterpret_cast<const ushort4*>(&src[(size_t)dd*4096 + m0 + q]);
    }
    int m1 = m0 + tid;
    int m2 = m0 + 128 + tid;
    for(int pass=0; pass<2; ++pass){
        int k = t + 2*pass;
        __syncthreads();
        for(int idx=tid; idx<2176; idx+=128){
            int c=idx>>6, dd=idx&63;
            Wt[dd][c]=xproj[k*2176+idx];
        }
        __syncthreads();
        float acc1[34], acc2[34];
        #pragma unroll
        for(int c=0;c<34;c++){ acc1[c]=0.f; acc2[c]=0.f; }
        for(int dd=0;dd<64;dd++){
            float u1 = b2f(tile[dd][tid]);
            float u2 = b2f(tile[dd][tid+128]);
            float wv[36];
            const float4* wp = reinterpret_cast<const float4*>(&Wt[dd][0]);
            *reinterpret_cast<float4*>(&wv[0])  = wp[0];
            *reinterpret_cast<float4*>(&wv[4])  = wp[1];
            *reinterpret_cast<float4*>(&wv[8])  = wp[2];
            *reinterpret_cast<float4*>(&wv[12]) = wp[3];
            *reinterpret_cast<float4*>(&wv[16]) = wp[4];
            *reinterpret_cast<float4*>(&wv[20]) = wp[5];
            *reinterpret_cast<float4*>(&wv[24]) = wp[6];
            *reinterpret_cast<float4*>(&wv[28]) = wp[7];
            *reinterpret_cast<float2*>(&wv[32]) = *reinterpret_cast<const float2*>(&Wt[dd][32]);
            #pragma unroll
            for(int c=0;c<34;c++){
                acc1[c] = fmaf(u1, wv[c], acc1[c]);
                acc2[c] = fmaf(u2, wv[c], acc2[c]);
            }
        }
        int l1 = pass ? (4095-m1) : m1;
        int l2 = pass ? (4095-m2) : m2;
        float* dt0 = DT + ((size_t)(ib*4+k)*2)*4096;
        ushort_t* ob = XBb + ((size_t)(ib*4+k)*16)*4096;
        ushort_t* oc = XCc + ((size_t)(ib*4+k)*16)*4096;
        dt0[l1]      = acc1[0];
        dt0[l2]      = acc2[0];
        dt0[4096+l1] = acc1[1];
        dt0[4096+l2] = acc2[1];
        #pragma unroll
        for(int c=0;c<16;c++){
            ob[(size_t)c*4096 + l1]=f2b(acc1[2+c]);
            ob[(size_t)c*4096 + l2]=f2b(acc2[2+c]);
            oc[(size_t)c*4096 + l1]=f2b(acc1[18+c]);
            oc[(size_t)c*4096 + l2]=f2b(acc2[18+c]);
        }
    }
}

// ================= scan kernels (CLEN=32, 128 chunks, XCD-pair swizzled) =================
__device__ __forceinline__ int chunk_swz(int c0){
    int xcd = c0 & 7, grp = c0 >> 3;
    return (grp >> 1)*16 + xcd*2 + (grp & 1);
}

template<bool UNI>
__device__ __forceinline__ void scan1_body(int w,int d,float dt0,float dt1,float db,
    const float* An, f32x2* h2, float& S,
    const float (*sB)[32][16], const float (*sdt)[32][2], const ushort_t (*su)[66])
{
    for(int t=0;t<32;t++){
        const float* dp=&sdt[w][t][0];
        float delta=softplus2(fmaf(dt0,dp[0],fmaf(dt1,dp[1],db)));
        S+=delta;
        int j = w? 31-t : t;
        float du = delta*b2f(su[j][d]);
        float bb[16];
        const float4* bp=reinterpret_cast<const float4*>(&sB[w][t][0]);
        reinterpret_cast<float4*>(bb)[0]=bp[0];
        reinterpret_cast<float4*>(bb)[1]=bp[1];
        reinterpret_cast<float4*>(bb)[2]=bp[2];
        reinterpret_cast<float4*>(bb)[3]=bp[3];
        if(UNI){
            float r1=__expf(delta*An[0]);
            float r2=r1*r1, r4=r2*r2, r8=r4*r4;
            f32x2 a0={r1,r2};
            f32x2 aa1=m2(a0,r2), aa2=m2(a0,r4), aa3=m2(aa1,r4);
            f32x2 aa4=m2(a0,r8), aa5=m2(aa1,r8), aa6=m2(aa2,r8), aa7=m2(aa3,r8);
            f32x2 du2={du,du};
            const f32x2* b2p=reinterpret_cast<const f32x2*>(bb);
            h2[0]=h2[0]*a0 +du2*b2p[0];
            h2[1]=h2[1]*aa1+du2*b2p[1];
            h2[2]=h2[2]*aa2+du2*b2p[2];
            h2[3]=h2[3]*aa3+du2*b2p[3];
            h2[4]=h2[4]*aa4+du2*b2p[4];
            h2[5]=h2[5]*aa5+du2*b2p[5];
            h2[6]=h2[6]*aa6+du2*b2p[6];
            h2[7]=h2[7]*aa7+du2*b2p[7];
        } else {
            float* hf=reinterpret_cast<float*>(h2);
            #pragma unroll
            for(int n=0;n<16;n++){ float a=__expf(delta*An[n]); hf[n]=fmaf(hf[n],a,du*bb[n]); }
        }
    }
}

__global__ __launch_bounds__(128) void k_scan1(const ushort_t* __restrict__ XBb, const float* __restrict__ DT,
        const ushort_t* __restrict__ XC, const ushort_t* __restrict__ XCT,
        const float* __restrict__ dtw, const float* __restrict__ dtb,
        const float* __restrict__ A_logs,
        ushort_t* __restrict__ CHS, float* __restrict__ SD){
    __shared__ float sB[2][32][16];
    __shared__ float sdt[2][32][2];
    __shared__ ushort_t su[32][66];
    int bid=blockIdx.x, tid=threadIdx.x;
    int ib = bid>>8; int rem = bid&255; int p = rem>>7; int ch = chunk_swz(rem&127);
    int w = tid>>6, d = tid&63;
    int l0 = ch*32, r0 = 4064 - l0;
    const ushort_t* B0 = XBb + (size_t)(4*ib+p)*16*4096;
    const ushort_t* B1 = XBb + (size_t)(4*ib+p+2)*16*4096;
    for(int idx=tid; idx<256; idx+=128){
        int n=idx&15, qi=(idx>>4)&7, w2=idx>>7;
        int base=(w2? r0 : l0) + qi*4;
        ushort4 v = *reinterpret_cast<const ushort4*>(&(w2?B1:B0)[(size_t)n*4096 + base]);
        int sl=qi*4;
        sB[w2][sl+0][n]=b2f(v.x); sB[w2][sl+1][n]=b2f(v.y);
        sB[w2][sl+2][n]=b2f(v.z); sB[w2][sl+3][n]=b2f(v.w);
    }
    {
        const float* D0 = DT + (size_t)(4*ib+p)*2*4096;
        const float* D1 = DT + (size_t)(4*ib+p+2)*2*4096;
        int w2=tid>>6; int rem2=tid&63; int s=rem2>>1; int r=rem2&1;
        sdt[w2][s][r]      = (w2? D1 : D0)[(size_t)r*4096 + (w2? r0 : l0) + s];
        sdt[w2][s+16][r]   = (w2? D1 : D0)[(size_t)r*4096 + (w2? r0 : l0) + s + 16];
    }
    const ushort_t* U = (p?XCT:XC) + (size_t)ib*64*4096;
    for(int idx=tid; idx<512; idx+=128){
        int r=idx>>3, q=(idx&7)*4;
        ushort4 v = *reinterpret_cast<const ushort4*>(&U[(size_t)r*4096 + l0 + q]);
        su[q+0][r]=v.x; su[q+1][r]=v.y; su[q+2][r]=v.z; su[q+3][r]=v.w;
    }
    __syncthreads();
    int k = p + 2*w;
    float dt0=dtw[(k*64+d)*2], dt1=dtw[(k*64+d)*2+1], db=dtb[k*64+d];
    float An[16];
    #pragma unroll
    for(int n=0;n<16;n++) An[n] = -__expf(A_logs[(k*64+d)*16+n]);
    bool st = true;
    #pragma unroll
    for(int n=1;n<16;n++) st = st && (fabsf(An[n]-(n+1)*An[0]) <= 1e-4f*fabsf(An[n]) + 1e-6f);
    bool uni = (bool)__all((int)st);
    f32x2 h2[8];
    #pragma unroll
    for(int i=0;i<8;i++){ h2[i].x=0.f; h2[i].y=0.f; }
    float S=0.f;
    if(uni) scan1_body<true >(w,d,dt0,dt1,db,An,h2,S,sB,sdt,su);
    else    scan1_body<false>(w,d,dt0,dt1,db,An,h2,S,sB,sdt,su);
    int chd = w ? 127-ch : ch;
    ushort_t* o = CHS + ((size_t)(4*ib+k)*128 + chd)*1024 + d*16;
    const float* hf = reinterpret_cast<const float*>(h2);
    #pragma unroll
    for(int n=0;n<16;n++) o[n]=f2b(hf[n]);
    SD[((size_t)(4*ib+k)*128 + chd)*64 + d]=S;
}

// ---- K5b: chunk-level exclusive scan (128 chunks, scan order); 4-way d-split ----
__global__ __launch_bounds__(256) void k_scan2(const float* __restrict__ A_logs,
        const float* __restrict__ SD, ushort_t* __restrict__ CHS){
    __shared__ float sS[2048];
    int g=blockIdx.x; int ibk=g>>2; int dg=g&3; int tid=threadIdx.x;
    for(int idx=tid; idx<2048; idx+=256){
        int c=idx>>4, dl=idx&15;
        sS[idx]=SD[((size_t)ibk*128+c)*64 + dg*16 + dl];
    }
    __syncthreads();
    int dl=tid>>4, n=tid&15, k=ibk&3;
    int d=dg*16+dl;
    float An = -__expf(A_logs[(k*64+d)*16+n]);
    float H=0.f;
    for(int c=0;c<128;c++){
        float pc = __expf(An*sS[c*16+dl]);
        size_t o = ((size_t)ibk*128+c)*1024 + dg*256 + tid;
        float loc = b2f(CHS[o]);
        CHS[o]=f2b(H);
        H = fmaf(H, pc, loc);
    }
}

// ---- K6: re-run chunks from entry states; wave0 keeps y in regs, wave1 stores y to sy;
//      single barrier; wave0 merges and writes spatial global rows directly ----
template<bool UNI>
__device__ __forceinline__ void scan3_run(int w,int d,float dt0,float dt1,float db,
    const float* An, f32x2* h2, float* yreg,
    const float (*sB)[32][16], const float (*sC)[32][16],
    const float (*sdt)[32][2], const ushort_t (*su)[66], ushort_t (*sy)[66])
{
    #pragma unroll
    for(int t=0;t<32;t++){
        const float* dp=&sdt[w][t][0];
        float delta=softplus2(fmaf(dt0,dp[0],fmaf(dt1,dp[1],db)));
        int j = w? 31-t : t;
        float du = delta*b2f(su[j][d]);
        float bb[16], cc[16];
        const float4* bp=reinterpret_cast<const float4*>(&sB[w][t][0]);
        const float4* cp=reinterpret_cast<const float4*>(&sC[w][t][0]);
        reinterpret_cast<float4*>(bb)[0]=bp[0]; reinterpret_cast<float4*>(bb)[1]=bp[1];
        reinterpret_cast<float4*>(bb)[2]=bp[2]; reinterpret_cast<float4*>(bb)[3]=bp[3];
        reinterpret_cast<float4*>(cc)[0]=cp[0]; reinterpret_cast<float4*>(cc)[1]=cp[1];
        reinterpret_cast<float4*>(cc)[2]=cp[2]; reinterpret_cast<float4*>(cc)[3]=cp[3];
        float y;
        if(UNI){
            float r1=__expf(delta*An[0]);
            float r2=r1*r1, r4=r2*r2, r8=r4*r4;
            f32x2 a0={r1,r2};
            f32x2 aa1=m2(a0,r2), aa2=m2(a0,r4), aa3=m2(aa1,r4);
            f32x2 aa4=m2(a0,r8), aa5=m2(aa1,r8), aa6=m2(aa2,r8), aa7=m2(aa3,r8);
            f32x2 du2={du,du};
            f32x2 y2={0.f,0.f};
            const f32x2* b2p=reinterpret_cast<const f32x2*>(bb);
            const f32x2* c2p=reinterpret_cast<const f32x2*>(cc);
            h2[0]=h2[0]*a0 +du2*b2p[0]; y2=y2+h2[0]*c2p[0];
            h2[1]=h2[1]*aa1+du2*b2p[1]; y2=y2+h2[1]*c2p[1];
            h2[2]=h2[2]*aa2+du2*b2p[2]; y2=y2+h2[2]*c2p[2];
            h2[3]=h2[3]*aa3+du2*b2p[3]; y2=y2+h2[3]*c2p[3];
            h2[4]=h2[4]*aa4+du2*b2p[4]; y2=y2+h2[4]*c2p[4];
            h2[5]=h2[5]*aa5+du2*b2p[5]; y2=y2+h2[5]*c2p[5];
            h2[6]=h2[6]*aa6+du2*b2p[6]; y2=y2+h2[6]*c2p[6];
            h2[7]=h2[7]*aa7+du2*b2p[7]; y2=y2+h2[7]*c2p[7];
            y = y2.x + y2.y;
        } else {
            y=0.f;
            float* hf=reinterpret_cast<float*>(h2);
            #pragma unroll
            for(int n=0;n<16;n++){
                float a=__expf(delta*An[n]);
                hf[n]=fmaf(hf[n],a,du*bb[n]);
                y=fmaf(hf[n],cc[n],y);
            }
        }
        if(w==0) yreg[t]=y;
        else     sy[j][d]=f2b(y);
    }
}

__global__ __launch_bounds__(128,4) void k_scan3(const ushort_t* __restrict__ XBb, const ushort_t* __restrict__ XCc,
        const float* __restrict__ DT,
        const ushort_t* __restrict__ XC, const ushort_t* __restrict__ XCT,
        const float* __restrict__ dtw, const float* __restrict__ dtb,
        const float* __restrict__ A_logs,
        const ushort_t* __restrict__ CHS,
        ushort_t* __restrict__ YS){
    __shared__ float sB[2][32][16];
    __shared__ float sC[2][32][16];
    __shared__ float sdt[2][32][2];
    __shared__ ushort_t su[32][66];
    __shared__ ushort_t sy[32][66];
    int bid=blockIdx.x, tid=threadIdx.x;
    int ib = bid>>8; int rem = bid&255; int p = rem>>7; int ch = chunk_swz(rem&127);
    int w = tid>>6, d = tid&63;
    int l0 = ch*32, r0 = 4064 - l0;
    const ushort_t* B0 = XBb + (size_t)(4*ib+p)*16*4096;
    const ushort_t* B1 = XBb + (size_t)(4*ib+p+2)*16*4096;
    const ushort_t* C0 = XCc + (size_t)(4*ib+p)*16*4096;
    const ushort_t* C1 = XCc + (size_t)(4*ib+p+2)*16*4096;
    for(int idx=tid; idx<512; idx+=128){
        int n=idx&15, qi=(idx>>4)&7, w2=(idx>>7)&1, arr=idx>>8;
        int base=(w2? r0 : l0) + qi*4;
        const ushort_t* S = arr? (w2?C1:C0) : (w2?B1:B0);
        ushort4 v = *reinterpret_cast<const ushort4*>(&S[(size_t)n*4096 + base]);
        float (*dst)[32][16] = arr? sC : sB;
        int sl=qi*4;
        dst[w2][sl+0][n]=b2f(v.x); dst[w2][sl+1][n]=b2f(v.y);
        dst[w2][sl+2][n]=b2f(v.z); dst[w2][sl+3][n]=b2f(v.w);
    }
    {
        const float* D0 = DT + (size_t)(4*ib+p)*2*4096;
        const float* D1 = DT + (size_t)(4*ib+p+2)*2*4096;
        int w2=tid>>6; int rem2=tid&63; int s=rem2>>1; int r=rem2&1;
        sdt[w2][s][r]      = (w2? D1 : D0)[(size_t)r*4096 + (w2? r0 : l0) + s];
        sdt[w2][s+16][r]   = (w2? D1 : D0)[(size_t)r*4096 + (w2? r0 : l0) + s + 16];
    }
    const ushort_t* U = (p?XCT:XC) + (size_t)ib*64*4096;
    for(int idx=tid; idx<512; idx+=128){
        int r=idx>>3, q=(idx&7)*4;
        ushort4 v = *reinterpret_cast<const ushort4*>(&U[(size_t)r*4096 + l0 + q]);
        su[q+0][r]=v.x; su[q+1][r]=v.y; su[q+2][r]=v.z; su[q+3][r]=v.w;
    }
    __syncthreads();
    int k = p + 2*w;
    float dt0=dtw[(k*64+d)*2], dt1=dtw[(k*64+d)*2+1], db=dtb[k*64+d];
    float An[16];
    #pragma unroll
    for(int n=0;n<16;n++) An[n] = -__expf(A_logs[(k*64+d)*16+n]);
    bool st = true;
    #pragma unroll
    for(int n=1;n<16;n++) st = st && (fabsf(An[n]-(n+1)*An[0]) <= 1e-4f*fabsf(An[n]) + 1e-6f);
    bool uni = (bool)__all((int)st);
    int chd = w ? 127-ch : ch;
    const ushort_t* e = CHS + ((size_t)(4*ib+k)*128 + chd)*1024 + d*16;
    f32x2 h2[8];
    {
        float* hf = reinterpret_cast<float*>(h2);
        #pragma unroll
        for(int n=0;n<16;n++) hf[n]=b2f(e[n]);
    }
    float yreg[32];
    if(uni) scan3_run<true >(w,d,dt0,dt1,db,An,h2,yreg,sB,sC,sdt,su,sy);
    else    scan3_run<false>(w,d,dt0,dt1,db,An,h2,yreg,sB,sC,sdt,su,sy);
    __syncthreads();
    if(w==0){
        ushort_t* plane = YS + (size_t)(ib*2+p)*262144;
        if(p==0){
            #pragma unroll
            for(int j=0;j<32;j++)
                plane[(size_t)(l0+j)*64 + d] = f2b(yreg[j] + b2f(sy[j][d]));
        } else {
            int hi = l0>>6, lo0 = l0&63;
            #pragma unroll
            for(int j=0;j<32;j++)
                plane[(size_t)(lo0+j)*4096 + hi*64 + d] = f2b(yreg[j] + b2f(sy[j][d]));
        }
    }
}

// ---- K8: out-LN(64) + gate + out-proj + residual + scale + BN + ReLU (f32 out) ----
__global__ __launch_bounds__(256) void k_final2(const ushort_t* __restrict__ YS,
        const ushort_t* __restrict__ ZS, const float* __restrict__ Y0,
        const ushort_t* __restrict__ XC, const float* __restrict__ Ds,
        const float* __restrict__ on_g, const float* __restrict__ on_b,
        const float* __restrict__ out_w,
        const float* __restrict__ s1, const float* __restrict__ s2, const float* __restrict__ s3,
        const float* __restrict__ bn_g, const float* __restrict__ bn_b,
        float* __restrict__ out){
    __shared__ float W[32*64];
    __shared__ float sD[64];
    int tid=threadIdx.x;
    for(int idx=tid; idx<512; idx+=256)
        *reinterpret_cast<float4*>(&W[idx*4]) = *reinterpret_cast<const float4*>(&out_w[idx*4]);
    if(tid<64) sD[tid]=Ds[tid]+Ds[64+tid]+Ds[128+tid]+Ds[192+tid];
    __syncthreads();
    int pg=blockIdx.x*256+tid;
    int ib=pg>>12, p=pg&4095;
    int i=ib>>3, b=ib&7;
    const ushort_t* r0p = YS + (size_t)(ib*2+0)*262144 + (size_t)p*64;
    const ushort_t* r1p = YS + (size_t)(ib*2+1)*262144 + (size_t)p*64;
    const ushort_t* xc = XC + (size_t)ib*64*4096 + p;
    float y[64];
    float mu=0.f;
    #pragma unroll
    for(int qq=0; qq<8; ++qq){
        ushort4 a0 = reinterpret_cast<const ushort4*>(r0p)[qq*2];
        ushort4 b0 = reinterpret_cast<const ushort4*>(r0p)[qq*2+1];
        ushort4 a1 = reinterpret_cast<const ushort4*>(r1p)[qq*2];
        ushort4 b1 = reinterpret_cast<const ushort4*>(r1p)[qq*2+1];
        const ushort_t* u0=reinterpret_cast<const ushort_t*>(&a0);
        const ushort_t* u1=reinterpret_cast<const ushort_t*>(&b0);
        const ushort_t* v0=reinterpret_cast<const ushort_t*>(&a1);
        const ushort_t* v1=reinterpret_cast<const ushort_t*>(&b1);
        #pragma unroll
        for(int e=0;e<4;e++){
            int dd=qq*8+e;
            y[dd]   = b2f(u0[e])+b2f(v0[e]) + sD[dd]  *b2f(xc[(size_t)dd*4096]);
            y[dd+4] = b2f(u1[e])+b2f(v1[e]) + sD[dd+4]*b2f(xc[(size_t)(dd+4)*4096]);
            mu += y[dd]+y[dd+4];
        }
    }
    mu*=(1.f/64.f);
    float v=0.f;
    #pragma unroll
    for(int dd=0;dd<64;dd++){ float q=y[dd]-mu; v+=q*q; }
    v*=(1.f/64.f);
    float rs=rsqrtf(v+1e-5f);
    const ushort_t* zs = ZS + (size_t)ib*64*4096 + p;
    #pragma unroll
    for(int dd=0;dd<64;dd++){
        float yn=(y[dd]-mu)*rs*on_g[dd]+on_b[dd];
        y[dd]=yn*b2f(zs[(size_t)dd*4096]);
    }
    float sc = (i==0)?s1[0]:((i==1)?s2[0]:s3[0]);
    const float inv = rsqrtf(1.00001f);
    const float* y0 = Y0 + (size_t)ib*32*4096 + p;
    for(int c=0;c<32;c++){
        float wv[64];
        const float4* wp = reinterpret_cast<const float4*>(&W[c*64]);
        #pragma unroll
        for(int q=0;q<16;q++) *reinterpret_cast<float4*>(&wv[q*4]) = wp[q];
        float a=0.f;
        #pragma unroll
        for(int dd=0;dd<64;dd++) a=fmaf(y[dd],wv[dd],a);
        float o=(y0[(size_t)c*4096]+a)*sc;
        int chn=i*32+c;
        float vv=fmaf(o*inv, bn_g[chn], bn_b[chn]);
        out[((size_t)b*128+chn)*4096 + p]=fmaxf(vv,0.f);
    }
}

// ---- K9: branch 4 passthrough * scale4 + BN + ReLU (f32 out) ----
__global__ __launch_bounds__(256) void k_branch4(const float* __restrict__ x,
        const float* __restrict__ s4, const float* __restrict__ bn_g,
        const float* __restrict__ bn_b, float* __restrict__ out){
    int g=blockIdx.x*256+threadIdx.x;
    int b=g>>17; int rem=g&131071; int c=rem>>12; int p=rem&4095;
    int chn=96+c;
    const float inv=rsqrtf(1.00001f);
    float v=x[((size_t)b*128+chn)*4096+p]*s4[0];
    v=fmaf(v*inv, bn_g[chn], bn_b[chn]);
    out[((size_t)b*128+chn)*4096+p]=fmaxf(v,0.f);
}

extern "C" void kernel_launch(void* const* d_in, const int* in_sizes, int n_in,
                              void* d_out, int out_size, void* d_ws, size_t ws_size,
                              hipStream_t stream) {
    const float* x      = (const float*)d_in[0];
    const float* ln_g   = (const float*)d_in[16];
    const float* ln_b   = (const float*)d_in[17];
    const float* in_w   = (const float*)d_in[18];
    const float* conv_w = (const float*)d_in[19];
    const float* conv_b = (const float*)d_in[20];
    const float* xproj  = (const float*)d_in[21];
    const float* dtw    = (const float*)d_in[22];
    const float* dtb    = (const float*)d_in[23];
    const float* A_logs = (const float*)d_in[24];
    const float* Ds     = (const float*)d_in[25];
    const float* on_g   = (const float*)d_in[26];
    const float* on_b   = (const float*)d_in[27];
    const float* out_w  = (const float*)d_in[28];
    const float* sc1    = (const float*)d_in[29];
    const float* sc2    = (const float*)d_in[30];
    const float* sc3    = (const float*)d_in[31];
    const float* sc4    = (const float*)d_in[32];
    const float* bn_g   = (const float*)d_in[33];
    const float* bn_b   = (const float*)d_in[34];

    AxialParams P;
    for(int i=0;i<3;i++){
        P.kh[i]=(const float*)d_in[1+5*i];
        P.kw[i]=(const float*)d_in[2+5*i];
        P.k3[i]=(const float*)d_in[3+5*i];
        P.g[i] =(const float*)d_in[4+5*i];
        P.b[i] =(const float*)d_in[5+5*i];
    }

    // ---- workspace layout (bytes); total 132,120,576 ----
    char* base = (char*)d_ws;
    float*    Y0   = (float*)   (base + 0);            // 12,582,912 f32
    ushort_t* ZS   = (ushort_t*)(base + 12582912);
    ushort_t* XC   = (ushort_t*)(base + 25165824);
    ushort_t* XCT  = (ushort_t*)(base + 37748736);
    ushort_t* XBb  = (ushort_t*)(base + 50331648);     // early alias: XW
    ushort_t* XW   = (ushort_t*)(base + 50331648);
    ushort_t* XCc  = (ushort_t*)(base + 62914560);
    float*    DT   = (float*)   (base + 75497472);     //  3,145,728 f32
    ushort_t* CHS  = (ushort_t*)(base + 78643200);     // 25,165,824 bf16 (128 chunks)
    float*    SD   = (float*)   (base + 103809024);    //  3,145,728 f32
    ushort_t* YS   = (ushort_t*)(base + 106954752);    // 25,165,824 bf16 (2 spatial planes/ib)

    float* out = (float*)d_out;

    k_axial    <<<768,   256, 0, stream>>>(x, Y0, P);
    k_lnproj   <<<384,   256, 0, stream>>>(Y0, ln_g, ln_b, in_w, XW, ZS);
    k_dwt      <<<1536,  256, 0, stream>>>(XW, conv_w, conv_b, XC, XCT);
    k_xdbl     <<<768,   128, 0, stream>>>(XC, XCT, xproj, XBb, XCc, DT);
    k_scan1    <<<6144,  128, 0, stream>>>(XBb, DT, XC, XCT, dtw, dtb, A_logs, CHS, SD);
    k_scan2    <<<384,   256, 0, stream>>>(A_logs, SD, CHS);
    k_scan3    <<<6144,  128, 0, stream>>>(XBb, XCc, DT, XC, XCT, dtw, dtb, A_logs, CHS, YS);
    k_final2   <<<384,   256, 0, stream>>>(YS, ZS, Y0, XC, Ds, on_g, on_b, out_w,
                                           sc1, sc2, sc3, bn_g, bn_b, out);
    k_branch4  <<<4096,  256, 0, stream>>>(x, sc4, bn_g, bn_b, out);
}